// Round 11
// baseline (177.825 us; speedup 1.0000x reference)
//
#include <hip/hip_runtime.h>
#include <hip/hip_bf16.h>
#include <stdint.h>

#define B_     8
#define TT     1024
#define DIM_   2048
#define S_     512
#define H_     16
#define DH     64
#define HID    1024

typedef _Float16 half8 __attribute__((ext_vector_type(8)));
typedef _Float16 half4v __attribute__((ext_vector_type(4)));
typedef float f32x4 __attribute__((ext_vector_type(4)));

__device__ __forceinline__ void gload_lds16(const void* g, void* l) {
  __builtin_amdgcn_global_load_lds(
      (__attribute__((address_space(1))) unsigned int*)(uintptr_t)g,
      (__attribute__((address_space(3))) unsigned int*)l, 16, 0, 0);
}

#define MFMA16(afv, bfv, nh)                                                  \
  do {                                                                        \
    __builtin_amdgcn_s_setprio(1);                                            \
    _Pragma("unroll")                                                         \
    for (int m_ = 0; m_ < 8; ++m_) {                                          \
      acc[m_][(nh)*2]   = __builtin_amdgcn_mfma_f32_16x16x32_f16(             \
          afv[m_], bfv[0], acc[m_][(nh)*2], 0, 0, 0);                         \
      acc[m_][(nh)*2+1] = __builtin_amdgcn_mfma_f32_16x16x32_f16(             \
          afv[m_], bfv[1], acc[m_][(nh)*2+1], 0, 0, 0);                       \
    }                                                                         \
    __builtin_amdgcn_s_setprio(0);                                            \
  } while (0)

// ---------------- fused prep: LN+cast, 3 weight transposes, media cast -----
// grid 18432 x 256: [0,8192) ln rows; [8192,10240) Wq^T; [10240,12288) Wkv^T;
// [12288,14336) Wo^T; [14336,18432) media f32->f16.
__device__ __forceinline__ void transpose_tile(
    const float* __restrict__ in, _Float16* __restrict__ out,
    int R, int C, int bx, int by, float (*t)[33])
{
  const int tid = threadIdx.x;
  const int tx = tid & 31, ty = tid >> 5;
  const int c0 = bx * 32, r0 = by * 32;
  #pragma unroll
  for (int i = 0; i < 32; i += 8)
    t[ty + i][tx] = in[(size_t)(r0 + ty + i) * C + c0 + tx];
  __syncthreads();
  #pragma unroll
  for (int i = 0; i < 32; i += 8)
    out[(size_t)(c0 + ty + i) * R + r0 + tx] = (_Float16)t[tx][ty + i];
}

__global__ __launch_bounds__(256) void prep(
    const float* __restrict__ x, const float* __restrict__ gamma,
    const float* __restrict__ beta, _Float16* __restrict__ xn,
    const float* __restrict__ Wq,  _Float16* __restrict__ wqT,
    const float* __restrict__ Wkv, _Float16* __restrict__ wkvT,
    const float* __restrict__ Wo,  _Float16* __restrict__ woT,
    const float* __restrict__ media, _Float16* __restrict__ mediah)
{
  __shared__ float t[32][33];
  const int id = blockIdx.x;
  const int tid = threadIdx.x;
  if (id < 8192) {
    // ---- LayerNorm + cast ----
    const float* xr = x + (size_t)id * DIM_;
    float4 a = ((const float4*)xr)[tid * 2];
    float4 b = ((const float4*)xr)[tid * 2 + 1];
    float s1 = a.x + a.y + a.z + a.w + b.x + b.y + b.z + b.w;
    float s2 = a.x*a.x + a.y*a.y + a.z*a.z + a.w*a.w
             + b.x*b.x + b.y*b.y + b.z*b.z + b.w*b.w;
    #pragma unroll
    for (int d = 1; d < 64; d <<= 1) {
      s1 += __shfl_xor(s1, d, 64);
      s2 += __shfl_xor(s2, d, 64);
    }
    const int w = tid >> 6, lane = tid & 63;
    if (lane == 0) { t[0][w] = s1; t[0][4 + w] = s2; }
    __syncthreads();
    s1 = t[0][0] + t[0][1] + t[0][2] + t[0][3];
    s2 = t[0][4] + t[0][5] + t[0][6] + t[0][7];
    const float mu  = s1 * (1.0f / DIM_);
    const float var = s2 * (1.0f / DIM_) - mu * mu;
    const float rs  = rsqrtf(var + 1e-5f);
    float4 g0 = ((const float4*)gamma)[tid * 2];
    float4 g1 = ((const float4*)gamma)[tid * 2 + 1];
    float4 e0 = ((const float4*)beta)[tid * 2];
    float4 e1 = ((const float4*)beta)[tid * 2 + 1];
    half8 o;
    o[0] = (_Float16)((a.x - mu) * rs * g0.x + e0.x);
    o[1] = (_Float16)((a.y - mu) * rs * g0.y + e0.y);
    o[2] = (_Float16)((a.z - mu) * rs * g0.z + e0.z);
    o[3] = (_Float16)((a.w - mu) * rs * g0.w + e0.w);
    o[4] = (_Float16)((b.x - mu) * rs * g1.x + e1.x);
    o[5] = (_Float16)((b.y - mu) * rs * g1.y + e1.y);
    o[6] = (_Float16)((b.z - mu) * rs * g1.z + e1.z);
    o[7] = (_Float16)((b.w - mu) * rs * g1.w + e1.w);
    *(half8*)(xn + (size_t)id * DIM_ + tid * 8) = o;
  } else if (id < 10240) {
    const int lid = id - 8192;                      // Wq [2048][1024] -> wqT
    transpose_tile(Wq, wqT, 2048, 1024, lid & 31, lid >> 5, t);
  } else if (id < 12288) {
    const int lid = id - 10240;                     // Wkv [1024][2048] -> wkvT
    transpose_tile(Wkv, wkvT, 1024, 2048, lid & 63, lid >> 6, t);
  } else if (id < 14336) {
    const int lid = id - 12288;                     // Wo [1024][2048] -> woT
    transpose_tile(Wo, woT, 1024, 2048, lid & 63, lid >> 6, t);
  } else {
    const int i = (id - 14336) * 256 + tid;         // media cast, n4 = 1048576
    float4 v = ((const float4*)media)[i];
    half4v o;
    o[0] = (_Float16)v.x; o[1] = (_Float16)v.y;
    o[2] = (_Float16)v.z; o[3] = (_Float16)v.w;
    ((half4v*)mediah)[i] = o;
  }
}

// ---------------- 128x128 GEMM, BK=32, 4 waves, m97-style loop -------------
// 32KB LDS -> 4 blocks/CU; inter-block overlap hides the stage stall.
// XOR swizzle chunk ^= (row>>1)&3 (residual 2-way = free).
template<typename OutT>
__device__ __forceinline__ void gemm128_body(
    const _Float16* __restrict__ A, const _Float16* __restrict__ BT,
    OutT* __restrict__ C, int KD, int ND, int m0, int n0,
    _Float16* __restrict__ sA, _Float16* __restrict__ sB)
{
  const int tid = threadIdx.x;
  const int lane = tid & 63, w = tid >> 6;
  const int l15 = lane & 15, lhi = lane >> 4;
  const int wr = w >> 1, wc = w & 1;
  const int rr = tid >> 2;
  const int sc = (tid & 3) ^ ((rr >> 1) & 3);

  auto stage = [&](const _Float16* __restrict__ G, int base, int k0,
                   _Float16* dst) {
    #pragma unroll
    for (int j = 0; j < 2; ++j) {
      const int r = j * 64 + rr;
      gload_lds16(G + (size_t)(base + r) * KD + k0 + sc * 8,
                  dst + j * 2048 + w * 512);
    }
  };

  f32x4 acc[4][4] = {};
  const int NT = KD >> 5;
  const int ck = lhi ^ ((l15 >> 1) & 3);

  stage(A, m0, 0, sA);
  stage(BT, n0, 0, sB);
  __syncthreads();
  int cur = 0;
  for (int kt = 0; kt < NT; ++kt) {
    if (kt + 1 < NT) {
      stage(A, m0, (kt + 1) * 32, sA + (cur ^ 1) * 4096);
      stage(BT, n0, (kt + 1) * 32, sB + (cur ^ 1) * 4096);
    }
    const _Float16* cA = sA + cur * 4096;
    const _Float16* cB = sB + cur * 4096;
    half8 af[4], bf[4];
    #pragma unroll
    for (int m = 0; m < 4; ++m)
      af[m] = *(const half8*)&cA[(wr * 64 + m * 16 + l15) * 32 + ck * 8];
    #pragma unroll
    for (int n = 0; n < 4; ++n)
      bf[n] = *(const half8*)&cB[(wc * 64 + n * 16 + l15) * 32 + ck * 8];
    #pragma unroll
    for (int m = 0; m < 4; ++m)
      #pragma unroll
      for (int n = 0; n < 4; ++n)
        acc[m][n] = __builtin_amdgcn_mfma_f32_16x16x32_f16(
            af[m], bf[n], acc[m][n], 0, 0, 0);
    __syncthreads();
    cur ^= 1;
  }

  #pragma unroll
  for (int m = 0; m < 4; ++m) {
    const int row = m0 + wr * 64 + m * 16 + lhi * 4;
    #pragma unroll
    for (int n = 0; n < 4; ++n) {
      const int col = n0 + wc * 64 + n * 16 + l15;
      #pragma unroll
      for (int r = 0; r < 4; ++r)
        C[(size_t)(row + r) * ND + col] = (OutT)acc[m][n][r];
    }
  }
}

// Fused Q + K + V^T: 512+256+256 = 1024 blocks = 4/CU (dynamic balancing;
// long Q blocks dispatched first). V^T GEMM eliminates build_vt.
__global__ __launch_bounds__(256, 4) void gemm_qkv(
    const _Float16* __restrict__ xn, const _Float16* __restrict__ wqT,
    _Float16* __restrict__ qh,
    const _Float16* __restrict__ mediah, const _Float16* __restrict__ wkvT,
    _Float16* __restrict__ kh, _Float16* __restrict__ vth)
{
  __shared__ __align__(16) _Float16 sA[2 * 4096], sB[2 * 4096];
  const int id = blockIdx.x;
  if (id < 512) {              // Q: M=8192 N=1024 K=2048
    const int m = id & 63, n = id >> 6;
    gemm128_body<_Float16>(xn, wqT, qh, 2048, 1024, m * 128, n * 128, sA, sB);
  } else if (id < 768) {       // K: M=4096 N=1024 K=1024
    const int lid = id - 512;
    const int m = lid & 31, n = lid >> 5;
    gemm128_body<_Float16>(mediah, wkvT, kh, 1024, 1024, m * 128, n * 128, sA, sB);
  } else {                     // V^T: M=1024 N=4096 K=1024
    const int lid = id - 768;
    const int m = lid & 7, n = lid >> 3;
    gemm128_body<_Float16>(wkvT + 1024 * 1024, mediah, vth, 1024, 4096,
                           m * 128, n * 128, sA, sB);
  }
}

// ---------------- 256x256 GEMM, BK=64, 8-phase counted-vmcnt (out-proj) ----
template<int KD, int ND, typename OutT>
__device__ __forceinline__ void gemm256_body(
    const _Float16* __restrict__ A, const _Float16* __restrict__ BT,
    OutT* __restrict__ C, int m0, int n0,
    _Float16* __restrict__ sAe, _Float16* __restrict__ sAo,
    _Float16* __restrict__ sBe, _Float16* __restrict__ sBo)
{
  constexpr int NT = KD / 64;
  constexpr int NI = NT / 2;
  const int tid = threadIdx.x;
  const int lane = tid & 63, w = tid >> 6;
  const int l15 = lane & 15, lhi = lane >> 4;
  const int wr = w >> 2, wc = w & 3;
  const int rs = l15 & 7;
  const int srow = tid >> 3;
  const int sch = (tid & 7) ^ (srow & 7);

  auto stage = [&](const _Float16* __restrict__ G, int base, int kt, int h,
                   _Float16* __restrict__ dst) {
    #pragma unroll
    for (int j = 0; j < 2; ++j) {
      const int r = h * 128 + j * 64 + srow;
      gload_lds16(G + (size_t)(base + r) * KD + kt * 64 + sch * 8,
                  dst + h * 8192 + j * 4096 + w * 512);
    }
  };

  f32x4 acc[8][4] = {};
  half8 af0[8], af1[8], bf0[2], bf1[2];

  stage(A,  m0, 0, 0, sAe); stage(A,  m0, 0, 1, sAe);
  stage(BT, n0, 0, 0, sBe); stage(BT, n0, 0, 1, sBe);
  stage(A,  m0, 1, 0, sAo); stage(A,  m0, 1, 1, sAo);
  asm volatile("s_waitcnt vmcnt(4)" ::: "memory");
  __builtin_amdgcn_s_barrier();

  for (int it = 0; it < NI; ++it) {
    const bool pf = (it + 1 < NI);
    const int t1 = 2 * it + 1, tn0 = 2 * it + 2, tn1 = 2 * it + 3;

    #pragma unroll
    for (int m = 0; m < 8; ++m)
      af0[m] = *(const half8*)&sAe[(wr*128 + m*16 + l15)*64 + ((lhi ^ rs)*8)];
    #pragma unroll
    for (int n = 0; n < 2; ++n)
      bf0[n] = *(const half8*)&sBe[(wc*64 + n*16 + l15)*64 + ((lhi ^ rs)*8)];
    stage(BT, n0, t1, 0, sBo);
    __builtin_amdgcn_s_barrier();
    asm volatile("s_waitcnt lgkmcnt(0)" ::: "memory");
    MFMA16(af0, bf0, 0);
    __builtin_amdgcn_s_barrier();
    #pragma unroll
    for (int m = 0; m < 8; ++m)
      af1[m] = *(const half8*)&sAe[(wr*128 + m*16 + l15)*64 + (((4+lhi) ^ rs)*8)];
    #pragma unroll
    for (int n = 0; n < 2; ++n)
      bf1[n] = *(const half8*)&sBe[(wc*64 + (2+n)*16 + l15)*64 + ((lhi ^ rs)*8)];
    stage(BT, n0, t1, 1, sBo);
    __builtin_amdgcn_s_barrier();
    asm volatile("s_waitcnt lgkmcnt(0)" ::: "memory");
    MFMA16(af0, bf1, 1);
    __builtin_amdgcn_s_barrier();
    #pragma unroll
    for (int n = 0; n < 2; ++n)
      bf0[n] = *(const half8*)&sBe[(wc*64 + n*16 + l15)*64 + (((4+lhi) ^ rs)*8)];
    if (pf) stage(A, m0, tn0, 0, sAe);
    __builtin_amdgcn_s_barrier();
    asm volatile("s_waitcnt lgkmcnt(0)" ::: "memory");
    MFMA16(af1, bf0, 0);
    __builtin_amdgcn_s_barrier();
    #pragma unroll
    for (int n = 0; n < 2; ++n)
      bf1[n] = *(const half8*)&sBe[(wc*64 + (2+n)*16 + l15)*64 + (((4+lhi) ^ rs)*8)];
    if (pf) stage(A, m0, tn0, 1, sAe);
    __builtin_amdgcn_s_barrier();
    asm volatile("s_waitcnt lgkmcnt(0)" ::: "memory");
    MFMA16(af1, bf1, 1);
    if (pf) asm volatile("s_waitcnt vmcnt(4)" ::: "memory");
    else    asm volatile("s_waitcnt vmcnt(0)" ::: "memory");
    __builtin_amdgcn_s_barrier();

    #pragma unroll
    for (int m = 0; m < 8; ++m)
      af0[m] = *(const half8*)&sAo[(wr*128 + m*16 + l15)*64 + ((lhi ^ rs)*8)];
    #pragma unroll
    for (int n = 0; n < 2; ++n)
      bf0[n] = *(const half8*)&sBo[(wc*64 + n*16 + l15)*64 + ((lhi ^ rs)*8)];
    if (pf) stage(BT, n0, tn0, 0, sBe);
    __builtin_amdgcn_s_barrier();
    asm volatile("s_waitcnt lgkmcnt(0)" ::: "memory");
    MFMA16(af0, bf0, 0);
    __builtin_amdgcn_s_barrier();
    #pragma unroll
    for (int m = 0; m < 8; ++m)
      af1[m] = *(const half8*)&sAo[(wr*128 + m*16 + l15)*64 + (((4+lhi) ^ rs)*8)];
    #pragma unroll
    for (int n = 0; n < 2; ++n)
      bf1[n] = *(const half8*)&sBo[(wc*64 + (2+n)*16 + l15)*64 + ((lhi ^ rs)*8)];
    if (pf) stage(BT, n0, tn0, 1, sBe);
    __builtin_amdgcn_s_barrier();
    asm volatile("s_waitcnt lgkmcnt(0)" ::: "memory");
    MFMA16(af0, bf1, 1);
    __builtin_amdgcn_s_barrier();
    #pragma unroll
    for (int n = 0; n < 2; ++n)
      bf0[n] = *(const half8*)&sBo[(wc*64 + n*16 + l15)*64 + (((4+lhi) ^ rs)*8)];
    if (pf) stage(A, m0, tn1, 0, sAo);
    __builtin_amdgcn_s_barrier();
    asm volatile("s_waitcnt lgkmcnt(0)" ::: "memory");
    MFMA16(af1, bf0, 0);
    __builtin_amdgcn_s_barrier();
    #pragma unroll
    for (int n = 0; n < 2; ++n)
      bf1[n] = *(const half8*)&sBo[(wc*64 + (2+n)*16 + l15)*64 + (((4+lhi) ^ rs)*8)];
    if (pf) stage(A, m0, tn1, 1, sAo);
    __builtin_amdgcn_s_barrier();
    asm volatile("s_waitcnt lgkmcnt(0)" ::: "memory");
    MFMA16(af1, bf1, 1);
    if (pf) asm volatile("s_waitcnt vmcnt(4)" ::: "memory");
    else    asm volatile("s_waitcnt vmcnt(0)" ::: "memory");
    __builtin_amdgcn_s_barrier();
  }

  #pragma unroll
  for (int mf = 0; mf < 8; ++mf) {
    const int row = m0 + wr * 128 + mf * 16 + lhi * 4;
    #pragma unroll
    for (int nf = 0; nf < 4; ++nf) {
      const int col = n0 + wc * 64 + nf * 16 + l15;
      #pragma unroll
      for (int r = 0; r < 4; ++r)
        C[(size_t)(row + r) * ND + col] = (OutT)acc[mf][nf][r];
    }
  }
}

// Out-proj: M=8192 N=2048 K=1024 -> 32 x 8 = 256 equal blocks = 1/CU.
__global__ __launch_bounds__(512, 2) void gemm_out(
    const _Float16* __restrict__ aoh, const _Float16* __restrict__ woT,
    float* __restrict__ out)
{
  __shared__ __align__(16) _Float16 sAe[256 * 64], sAo[256 * 64];
  __shared__ __align__(16) _Float16 sBe[256 * 64], sBo[256 * 64];
  const int id = blockIdx.x;
  const int m = id & 31, n = id >> 5;
  gemm256_body<1024, 2048, float>(aoh, woT, out, m * 256, n * 256,
                                  sAe, sAo, sBe, sBo);
}

// ---------------- fused attention: swapped QK^T, lane-local softmax --------
__global__ __launch_bounds__(512, 6) void attn_kernel(
    const _Float16* __restrict__ q, const _Float16* __restrict__ kh,
    const _Float16* __restrict__ vt, _Float16* __restrict__ ao)
{
  __shared__ __align__(16) _Float16 Ks[2][64 * 64];
  __shared__ __align__(16) _Float16 Vs[2][64 * 64];
  __shared__ __align__(16) _Float16 P[8][16 * 64];
  const int tid = threadIdx.x;
  const int lane = tid & 63, w = tid >> 6;
  const int l15 = lane & 15, lhi = lane >> 4;
  const int id = blockIdx.x;
  const int bh = id & 127, tb = id >> 7;
  const int b = bh >> 4, h = bh & 15;
  const int t0 = tb * 128 + w * 16;

  const _Float16* qp = q + (size_t)(b * TT + t0 + l15) * HID + h * DH + lhi * 8;
  half8 aq0 = *(const half8*)qp;
  half8 aq1 = *(const half8*)(qp + 32);

  const int srow = lane >> 3;
  const int sj   = (lane & 7) ^ srow;
  const _Float16* kbase = kh + (size_t)(b * S_) * 1024 + h * DH;
  const _Float16* vbase = vt + (size_t)(h * DH) * 4096 + b * S_;

  auto stageK = [&](int c, int pg) {
    const int r = w * 8 + srow;
    gload_lds16(kbase + (size_t)(c * 64 + r) * 1024 + sj * 8, &Ks[pg][w * 512]);
  };
  auto stageV = [&](int c, int pg) {
    const int r = w * 8 + srow;
    gload_lds16(vbase + (size_t)r * 4096 + c * 64 + sj * 8, &Vs[pg][w * 512]);
  };

  f32x4 acco[4] = {};
  float m_ = -1e30f, l_ = 0.f;

  const int key = l15 & 7;
  const int ck0 = lhi ^ key;
  const int swr = key << 3;

  stageK(0, 0); stageV(0, 0);
  __syncthreads();
  int cur = 0;
  for (int c = 0; c < 8; ++c) {
    if (c + 1 < 8) { stageK(c + 1, cur ^ 1); stageV(c + 1, cur ^ 1); }
    f32x4 accs[4] = {};
    __builtin_amdgcn_s_setprio(1);
    #pragma unroll
    for (int n = 0; n < 4; ++n) {
      const int row = n * 16 + l15;
      half8 kf0 = *(const half8*)&Ks[cur][row * 64 + ck0 * 8];
      half8 kf1 = *(const half8*)&Ks[cur][row * 64 + (ck0 ^ 4) * 8];
      accs[n] = __builtin_amdgcn_mfma_f32_16x16x32_f16(kf0, aq0, accs[n], 0, 0, 0);
      accs[n] = __builtin_amdgcn_mfma_f32_16x16x32_f16(kf1, aq1, accs[n], 0, 0, 0);
    }
    __builtin_amdgcn_s_setprio(0);
    float c0 = fmaxf(fmaxf(accs[0][0], accs[0][1]), fmaxf(accs[0][2], accs[0][3]));
    float c1 = fmaxf(fmaxf(accs[1][0], accs[1][1]), fmaxf(accs[1][2], accs[1][3]));
    float c2 = fmaxf(fmaxf(accs[2][0], accs[2][1]), fmaxf(accs[2][2], accs[2][3]));
    float c3 = fmaxf(fmaxf(accs[3][0], accs[3][1]), fmaxf(accs[3][2], accs[3][3]));
    float mx = fmaxf(fmaxf(c0, c1), fmaxf(c2, c3));
    mx = fmaxf(mx, __shfl_xor(mx, 16, 64));
    mx = fmaxf(mx, __shfl_xor(mx, 32, 64));
    const float mnew = fmaxf(m_, mx);
    const float scale = __expf(m_ - mnew);
    m_ = mnew;
    #pragma unroll
    for (int n = 0; n < 4; ++n)
      #pragma unroll
      for (int r = 0; r < 4; ++r)
        accs[n][r] = __expf(accs[n][r] - mnew);
    float s0 = (accs[0][0] + accs[0][1]) + (accs[0][2] + accs[0][3]);
    float s1 = (accs[1][0] + accs[1][1]) + (accs[1][2] + accs[1][3]);
    float s2 = (accs[2][0] + accs[2][1]) + (accs[2][2] + accs[2][3]);
    float s3 = (accs[3][0] + accs[3][1]) + (accs[3][2] + accs[3][3]);
    float sm = (s0 + s1) + (s2 + s3);
    sm += __shfl_xor(sm, 16, 64);
    sm += __shfl_xor(sm, 32, 64);
    l_ = l_ * scale + sm;
    #pragma unroll
    for (int n = 0; n < 4; ++n) {
      half4v pw;
      pw[0] = (_Float16)accs[n][0]; pw[1] = (_Float16)accs[n][1];
      pw[2] = (_Float16)accs[n][2]; pw[3] = (_Float16)accs[n][3];
      const int base = (n * 16 + lhi * 4) ^ swr;
      *(half4v*)&P[w][l15 * 64 + base] = pw;
    }
    #pragma unroll
    for (int r = 0; r < 4; ++r) {
      const float s_r = __shfl(scale, (lane >> 4) * 4 + r, 16);
      #pragma unroll
      for (int n = 0; n < 4; ++n) acco[n][r] *= s_r;
    }
    __builtin_amdgcn_s_setprio(1);
    #pragma unroll
    for (int ks = 0; ks < 2; ++ks) {
      half8 ap = *(const half8*)&P[w][l15 * 64 + ((ks * 32 + lhi * 8) ^ swr)];
      #pragma unroll
      for (int n = 0; n < 4; ++n) {
        const int row = n * 16 + l15;
        half8 vf = *(const half8*)&Vs[cur][row * 64 + ((ks * 4 + lhi) ^ key) * 8];
        acco[n] = __builtin_amdgcn_mfma_f32_16x16x32_f16(ap, vf, acco[n], 0, 0, 0);
      }
    }
    __builtin_amdgcn_s_setprio(0);
    __syncthreads();
    cur ^= 1;
  }
  const float inv = 1.0f / (l_ * 8.0f);
  #pragma unroll
  for (int r = 0; r < 4; ++r) {
    const float inv_r = __shfl(inv, (lane >> 4) * 4 + r, 16);
    const int qrow = lhi * 4 + r;
    const int kq = qrow & 7;
    #pragma unroll
    for (int n = 0; n < 4; ++n) {
      const int d = n * 16 + l15;
      P[w][qrow * 64 + (((d >> 3) ^ kq) * 8) + (d & 7)] =
          (_Float16)(acco[n][r] * inv_r);
    }
  }
  const int q2 = lane >> 2;
  const int kq2 = q2 & 7;
  const int g0 = ((lane & 3) * 2) ^ kq2;
  const int g1 = ((lane & 3) * 2 + 1) ^ kq2;
  half8 o0 = *(const half8*)&P[w][q2 * 64 + g0 * 8];
  half8 o1 = *(const half8*)&P[w][q2 * 64 + g1 * 8];
  _Float16* op = ao + (size_t)(b * TT + t0 + q2) * HID + h * DH + (lane & 3) * 16;
  *(half8*)op = o0;
  *(half8*)(op + 8) = o1;
}

extern "C" void kernel_launch(void* const* d_in, const int* in_sizes, int n_in,
                              void* d_out, int out_size, void* d_ws, size_t ws_size,
                              hipStream_t stream) {
  const float* x     = (const float*)d_in[0];
  const float* media = (const float*)d_in[1];
  // d_in[2] media_locations: unused (reference discards the mask)
  const float* Wq    = (const float*)d_in[3];
  const float* Wkv   = (const float*)d_in[4];
  const float* Wo    = (const float*)d_in[5];
  const float* gamma = (const float*)d_in[6];
  const float* beta  = (const float*)d_in[7];
  float* out = (float*)d_out;

  char* ws = (char*)d_ws;
  _Float16* xn     = (_Float16*)(ws);                    // 8192x2048 (32MB)
  _Float16* qh     = (_Float16*)(ws + 33554432);         // 8192x1024 (16MB)
  _Float16* kh     = (_Float16*)(ws + 50331648);         // 4096x1024 (8MB)
  _Float16* vth    = (_Float16*)(ws + 58720256);         // 1024x4096 (8MB)
  _Float16* aoh    = (_Float16*)(ws + 67108864);         // 8192x1024 (16MB)
  _Float16* mediah = (_Float16*)(ws + 83886080);         // 4096x1024 (8MB)
  _Float16* wqT    = (_Float16*)(ws + 92274688);         // 1024x2048 (4MB)
  _Float16* wkvT   = (_Float16*)(ws + 96468992);         // 2048x1024 (4MB)
  _Float16* woT    = (_Float16*)(ws + 100663296);        // 2048x1024 (4MB)

  prep<<<dim3(18432), dim3(256), 0, stream>>>(
      x, gamma, beta, xn, Wq, wqT, Wkv, wkvT, Wo, woT, media, mediah);
  gemm_qkv<<<dim3(1024), dim3(256), 0, stream>>>(xn, wqT, qh, mediah, wkvT, kh, vth);
  attn_kernel<<<dim3(1024), dim3(512), 0, stream>>>(qh, kh, vth, aoh);
  gemm_out<<<dim3(256), dim3(512), 0, stream>>>(aoh, woT, out);
}

// Round 12
// 172.119 us; speedup vs baseline: 1.0331x; 1.0331x over previous
//
#include <hip/hip_runtime.h>
#include <hip/hip_bf16.h>
#include <stdint.h>

#define B_     8
#define TT     1024
#define DIM_   2048
#define S_     512
#define H_     16
#define DH     64
#define HID    1024

typedef _Float16 half8 __attribute__((ext_vector_type(8)));
typedef _Float16 half4v __attribute__((ext_vector_type(4)));
typedef float f32x4 __attribute__((ext_vector_type(4)));

__device__ __forceinline__ void gload_lds16(const void* g, void* l) {
  __builtin_amdgcn_global_load_lds(
      (__attribute__((address_space(1))) unsigned int*)(uintptr_t)g,
      (__attribute__((address_space(3))) unsigned int*)l, 16, 0, 0);
}

#define MFMA16(afv, bfv, nh)                                                  \
  do {                                                                        \
    __builtin_amdgcn_s_setprio(1);                                            \
    _Pragma("unroll")                                                         \
    for (int m_ = 0; m_ < 8; ++m_) {                                          \
      acc[m_][(nh)*2]   = __builtin_amdgcn_mfma_f32_16x16x32_f16(             \
          afv[m_], bfv[0], acc[m_][(nh)*2], 0, 0, 0);                         \
      acc[m_][(nh)*2+1] = __builtin_amdgcn_mfma_f32_16x16x32_f16(             \
          afv[m_], bfv[1], acc[m_][(nh)*2+1], 0, 0, 0);                       \
    }                                                                         \
    __builtin_amdgcn_s_setprio(0);                                            \
  } while (0)

// ---------------- fused prep: LN+cast, 3 weight transposes, media cast -----
__device__ __forceinline__ void transpose_tile(
    const float* __restrict__ in, _Float16* __restrict__ out,
    int R, int C, int bx, int by, float (*t)[33])
{
  const int tid = threadIdx.x;
  const int tx = tid & 31, ty = tid >> 5;
  const int c0 = bx * 32, r0 = by * 32;
  #pragma unroll
  for (int i = 0; i < 32; i += 8)
    t[ty + i][tx] = in[(size_t)(r0 + ty + i) * C + c0 + tx];
  __syncthreads();
  #pragma unroll
  for (int i = 0; i < 32; i += 8)
    out[(size_t)(c0 + ty + i) * R + r0 + tx] = (_Float16)t[tx][ty + i];
}

__global__ __launch_bounds__(256) void prep(
    const float* __restrict__ x, const float* __restrict__ gamma,
    const float* __restrict__ beta, _Float16* __restrict__ xn,
    const float* __restrict__ Wq,  _Float16* __restrict__ wqT,
    const float* __restrict__ Wkv, _Float16* __restrict__ wkvT,
    const float* __restrict__ Wo,  _Float16* __restrict__ woT,
    const float* __restrict__ media, _Float16* __restrict__ mediah)
{
  __shared__ float t[32][33];
  const int id = blockIdx.x;
  const int tid = threadIdx.x;
  if (id < 8192) {
    const float* xr = x + (size_t)id * DIM_;
    float4 a = ((const float4*)xr)[tid * 2];
    float4 b = ((const float4*)xr)[tid * 2 + 1];
    float s1 = a.x + a.y + a.z + a.w + b.x + b.y + b.z + b.w;
    float s2 = a.x*a.x + a.y*a.y + a.z*a.z + a.w*a.w
             + b.x*b.x + b.y*b.y + b.z*b.z + b.w*b.w;
    #pragma unroll
    for (int d = 1; d < 64; d <<= 1) {
      s1 += __shfl_xor(s1, d, 64);
      s2 += __shfl_xor(s2, d, 64);
    }
    const int w = tid >> 6, lane = tid & 63;
    if (lane == 0) { t[0][w] = s1; t[0][4 + w] = s2; }
    __syncthreads();
    s1 = t[0][0] + t[0][1] + t[0][2] + t[0][3];
    s2 = t[0][4] + t[0][5] + t[0][6] + t[0][7];
    const float mu  = s1 * (1.0f / DIM_);
    const float var = s2 * (1.0f / DIM_) - mu * mu;
    const float rs  = rsqrtf(var + 1e-5f);
    float4 g0 = ((const float4*)gamma)[tid * 2];
    float4 g1 = ((const float4*)gamma)[tid * 2 + 1];
    float4 e0 = ((const float4*)beta)[tid * 2];
    float4 e1 = ((const float4*)beta)[tid * 2 + 1];
    half8 o;
    o[0] = (_Float16)((a.x - mu) * rs * g0.x + e0.x);
    o[1] = (_Float16)((a.y - mu) * rs * g0.y + e0.y);
    o[2] = (_Float16)((a.z - mu) * rs * g0.z + e0.z);
    o[3] = (_Float16)((a.w - mu) * rs * g0.w + e0.w);
    o[4] = (_Float16)((b.x - mu) * rs * g1.x + e1.x);
    o[5] = (_Float16)((b.y - mu) * rs * g1.y + e1.y);
    o[6] = (_Float16)((b.z - mu) * rs * g1.z + e1.z);
    o[7] = (_Float16)((b.w - mu) * rs * g1.w + e1.w);
    *(half8*)(xn + (size_t)id * DIM_ + tid * 8) = o;
  } else if (id < 10240) {
    const int lid = id - 8192;
    transpose_tile(Wq, wqT, 2048, 1024, lid & 31, lid >> 5, t);
  } else if (id < 12288) {
    const int lid = id - 10240;
    transpose_tile(Wkv, wkvT, 1024, 2048, lid & 63, lid >> 6, t);
  } else if (id < 14336) {
    const int lid = id - 12288;
    transpose_tile(Wo, woT, 1024, 2048, lid & 63, lid >> 6, t);
  } else {
    const int i = (id - 14336) * 256 + tid;
    float4 v = ((const float4*)media)[i];
    half4v o;
    o[0] = (_Float16)v.x; o[1] = (_Float16)v.y;
    o[2] = (_Float16)v.z; o[3] = (_Float16)v.w;
    ((half4v*)mediah)[i] = o;
  }
}

// ---------------- 128x128 GEMM, BK=32, 4 waves, m97-style loop -------------
template<typename OutT>
__device__ __forceinline__ void gemm128_body(
    const _Float16* __restrict__ A, const _Float16* __restrict__ BT,
    OutT* __restrict__ C, int KD, int ND, int m0, int n0,
    _Float16* __restrict__ sA, _Float16* __restrict__ sB)
{
  const int tid = threadIdx.x;
  const int lane = tid & 63, w = tid >> 6;
  const int l15 = lane & 15, lhi = lane >> 4;
  const int wr = w >> 1, wc = w & 1;
  const int rr = tid >> 2;
  const int sc = (tid & 3) ^ ((rr >> 1) & 3);

  auto stage = [&](const _Float16* __restrict__ G, int base, int k0,
                   _Float16* dst) {
    #pragma unroll
    for (int j = 0; j < 2; ++j) {
      const int r = j * 64 + rr;
      gload_lds16(G + (size_t)(base + r) * KD + k0 + sc * 8,
                  dst + j * 2048 + w * 512);
    }
  };

  f32x4 acc[4][4] = {};
  const int NT = KD >> 5;
  const int ck = lhi ^ ((l15 >> 1) & 3);

  stage(A, m0, 0, sA);
  stage(BT, n0, 0, sB);
  __syncthreads();
  int cur = 0;
  for (int kt = 0; kt < NT; ++kt) {
    if (kt + 1 < NT) {
      stage(A, m0, (kt + 1) * 32, sA + (cur ^ 1) * 4096);
      stage(BT, n0, (kt + 1) * 32, sB + (cur ^ 1) * 4096);
    }
    const _Float16* cA = sA + cur * 4096;
    const _Float16* cB = sB + cur * 4096;
    half8 af[4], bf[4];
    #pragma unroll
    for (int m = 0; m < 4; ++m)
      af[m] = *(const half8*)&cA[(wr * 64 + m * 16 + l15) * 32 + ck * 8];
    #pragma unroll
    for (int n = 0; n < 4; ++n)
      bf[n] = *(const half8*)&cB[(wc * 64 + n * 16 + l15) * 32 + ck * 8];
    #pragma unroll
    for (int m = 0; m < 4; ++m)
      #pragma unroll
      for (int n = 0; n < 4; ++n)
        acc[m][n] = __builtin_amdgcn_mfma_f32_16x16x32_f16(
            af[m], bf[n], acc[m][n], 0, 0, 0);
    __syncthreads();
    cur ^= 1;
  }

  #pragma unroll
  for (int m = 0; m < 4; ++m) {
    const int row = m0 + wr * 64 + m * 16 + lhi * 4;
    #pragma unroll
    for (int n = 0; n < 4; ++n) {
      const int col = n0 + wc * 64 + n * 16 + l15;
      #pragma unroll
      for (int r = 0; r < 4; ++r)
        C[(size_t)(row + r) * ND + col] = (OutT)acc[m][n][r];
    }
  }
}

// Fused Q + K + V^T: 512+256+256 = 1024 blocks = 4/CU.
__global__ __launch_bounds__(256, 4) void gemm_qkv(
    const _Float16* __restrict__ xn, const _Float16* __restrict__ wqT,
    _Float16* __restrict__ qh,
    const _Float16* __restrict__ mediah, const _Float16* __restrict__ wkvT,
    _Float16* __restrict__ kh, _Float16* __restrict__ vth)
{
  __shared__ __align__(16) _Float16 sA[2 * 4096], sB[2 * 4096];
  const int id = blockIdx.x;
  if (id < 512) {              // Q: M=8192 N=1024 K=2048
    const int m = id & 63, n = id >> 6;
    gemm128_body<_Float16>(xn, wqT, qh, 2048, 1024, m * 128, n * 128, sA, sB);
  } else if (id < 768) {       // K: M=4096 N=1024 K=1024
    const int lid = id - 512;
    const int m = lid & 31, n = lid >> 5;
    gemm128_body<_Float16>(mediah, wkvT, kh, 1024, 1024, m * 128, n * 128, sA, sB);
  } else {                     // V^T: M=1024 N=4096 K=1024
    const int lid = id - 768;
    const int m = lid & 7, n = lid >> 3;
    gemm128_body<_Float16>(wkvT + 1024 * 1024, mediah, vth, 1024, 4096,
                           m * 128, n * 128, sA, sB);
  }
}

// ---------------- 256x256 GEMM, BK=64, 8-phase counted-vmcnt (out-proj) ----
template<int KD, int ND, typename OutT>
__device__ __forceinline__ void gemm256_body(
    const _Float16* __restrict__ A, const _Float16* __restrict__ BT,
    OutT* __restrict__ C, int m0, int n0,
    _Float16* __restrict__ sAe, _Float16* __restrict__ sAo,
    _Float16* __restrict__ sBe, _Float16* __restrict__ sBo)
{
  constexpr int NT = KD / 64;
  constexpr int NI = NT / 2;
  const int tid = threadIdx.x;
  const int lane = tid & 63, w = tid >> 6;
  const int l15 = lane & 15, lhi = lane >> 4;
  const int wr = w >> 2, wc = w & 3;
  const int rs = l15 & 7;
  const int srow = tid >> 3;
  const int sch = (tid & 7) ^ (srow & 7);

  auto stage = [&](const _Float16* __restrict__ G, int base, int kt, int h,
                   _Float16* __restrict__ dst) {
    #pragma unroll
    for (int j = 0; j < 2; ++j) {
      const int r = h * 128 + j * 64 + srow;
      gload_lds16(G + (size_t)(base + r) * KD + kt * 64 + sch * 8,
                  dst + h * 8192 + j * 4096 + w * 512);
    }
  };

  f32x4 acc[8][4] = {};
  half8 af0[8], af1[8], bf0[2], bf1[2];

  stage(A,  m0, 0, 0, sAe); stage(A,  m0, 0, 1, sAe);
  stage(BT, n0, 0, 0, sBe); stage(BT, n0, 0, 1, sBe);
  stage(A,  m0, 1, 0, sAo); stage(A,  m0, 1, 1, sAo);
  asm volatile("s_waitcnt vmcnt(4)" ::: "memory");
  __builtin_amdgcn_s_barrier();

  for (int it = 0; it < NI; ++it) {
    const bool pf = (it + 1 < NI);
    const int t1 = 2 * it + 1, tn0 = 2 * it + 2, tn1 = 2 * it + 3;

    #pragma unroll
    for (int m = 0; m < 8; ++m)
      af0[m] = *(const half8*)&sAe[(wr*128 + m*16 + l15)*64 + ((lhi ^ rs)*8)];
    #pragma unroll
    for (int n = 0; n < 2; ++n)
      bf0[n] = *(const half8*)&sBe[(wc*64 + n*16 + l15)*64 + ((lhi ^ rs)*8)];
    stage(BT, n0, t1, 0, sBo);
    __builtin_amdgcn_s_barrier();
    asm volatile("s_waitcnt lgkmcnt(0)" ::: "memory");
    MFMA16(af0, bf0, 0);
    __builtin_amdgcn_s_barrier();
    #pragma unroll
    for (int m = 0; m < 8; ++m)
      af1[m] = *(const half8*)&sAe[(wr*128 + m*16 + l15)*64 + (((4+lhi) ^ rs)*8)];
    #pragma unroll
    for (int n = 0; n < 2; ++n)
      bf1[n] = *(const half8*)&sBe[(wc*64 + (2+n)*16 + l15)*64 + ((lhi ^ rs)*8)];
    stage(BT, n0, t1, 1, sBo);
    __builtin_amdgcn_s_barrier();
    asm volatile("s_waitcnt lgkmcnt(0)" ::: "memory");
    MFMA16(af0, bf1, 1);
    __builtin_amdgcn_s_barrier();
    #pragma unroll
    for (int n = 0; n < 2; ++n)
      bf0[n] = *(const half8*)&sBe[(wc*64 + n*16 + l15)*64 + (((4+lhi) ^ rs)*8)];
    if (pf) stage(A, m0, tn0, 0, sAe);
    __builtin_amdgcn_s_barrier();
    asm volatile("s_waitcnt lgkmcnt(0)" ::: "memory");
    MFMA16(af1, bf0, 0);
    __builtin_amdgcn_s_barrier();
    #pragma unroll
    for (int n = 0; n < 2; ++n)
      bf1[n] = *(const half8*)&sBe[(wc*64 + (2+n)*16 + l15)*64 + (((4+lhi) ^ rs)*8)];
    if (pf) stage(A, m0, tn0, 1, sAe);
    __builtin_amdgcn_s_barrier();
    asm volatile("s_waitcnt lgkmcnt(0)" ::: "memory");
    MFMA16(af1, bf1, 1);
    if (pf) asm volatile("s_waitcnt vmcnt(4)" ::: "memory");
    else    asm volatile("s_waitcnt vmcnt(0)" ::: "memory");
    __builtin_amdgcn_s_barrier();

    #pragma unroll
    for (int m = 0; m < 8; ++m)
      af0[m] = *(const half8*)&sAo[(wr*128 + m*16 + l15)*64 + ((lhi ^ rs)*8)];
    #pragma unroll
    for (int n = 0; n < 2; ++n)
      bf0[n] = *(const half8*)&sBo[(wc*64 + n*16 + l15)*64 + ((lhi ^ rs)*8)];
    if (pf) stage(BT, n0, tn0, 0, sBe);
    __builtin_amdgcn_s_barrier();
    asm volatile("s_waitcnt lgkmcnt(0)" ::: "memory");
    MFMA16(af0, bf0, 0);
    __builtin_amdgcn_s_barrier();
    #pragma unroll
    for (int m = 0; m < 8; ++m)
      af1[m] = *(const half8*)&sAo[(wr*128 + m*16 + l15)*64 + (((4+lhi) ^ rs)*8)];
    #pragma unroll
    for (int n = 0; n < 2; ++n)
      bf1[n] = *(const half8*)&sBo[(wc*64 + (2+n)*16 + l15)*64 + ((lhi ^ rs)*8)];
    if (pf) stage(BT, n0, tn0, 1, sBe);
    __builtin_amdgcn_s_barrier();
    asm volatile("s_waitcnt lgkmcnt(0)" ::: "memory");
    MFMA16(af0, bf1, 1);
    __builtin_amdgcn_s_barrier();
    #pragma unroll
    for (int n = 0; n < 2; ++n)
      bf0[n] = *(const half8*)&sBo[(wc*64 + n*16 + l15)*64 + (((4+lhi) ^ rs)*8)];
    if (pf) stage(A, m0, tn1, 0, sAo);
    __builtin_amdgcn_s_barrier();
    asm volatile("s_waitcnt lgkmcnt(0)" ::: "memory");
    MFMA16(af1, bf0, 0);
    __builtin_amdgcn_s_barrier();
    #pragma unroll
    for (int n = 0; n < 2; ++n)
      bf1[n] = *(const half8*)&sBo[(wc*64 + (2+n)*16 + l15)*64 + (((4+lhi) ^ rs)*8)];
    if (pf) stage(A, m0, tn1, 1, sAo);
    __builtin_amdgcn_s_barrier();
    asm volatile("s_waitcnt lgkmcnt(0)" ::: "memory");
    MFMA16(af1, bf1, 1);
    if (pf) asm volatile("s_waitcnt vmcnt(4)" ::: "memory");
    else    asm volatile("s_waitcnt vmcnt(0)" ::: "memory");
    __builtin_amdgcn_s_barrier();
  }

  #pragma unroll
  for (int mf = 0; mf < 8; ++mf) {
    const int row = m0 + wr * 128 + mf * 16 + lhi * 4;
    #pragma unroll
    for (int nf = 0; nf < 4; ++nf) {
      const int col = n0 + wc * 64 + nf * 16 + l15;
      #pragma unroll
      for (int r = 0; r < 4; ++r)
        C[(size_t)(row + r) * ND + col] = (OutT)acc[mf][nf][r];
    }
  }
}

__global__ __launch_bounds__(512, 2) void gemm_out(
    const _Float16* __restrict__ aoh, const _Float16* __restrict__ woT,
    float* __restrict__ out)
{
  __shared__ __align__(16) _Float16 sAe[256 * 64], sAo[256 * 64];
  __shared__ __align__(16) _Float16 sBe[256 * 64], sBo[256 * 64];
  const int id = blockIdx.x;
  const int m = id & 31, n = id >> 5;
  gemm256_body<1024, 2048, float>(aoh, woT, out, m * 256, n * 256,
                                  sAe, sAo, sBe, sBo);
}

// ---------------- fused attention v7: KVBLK=128, defer-max ----------------
// 4 chunks of 128 s-rows (half the barriers/softmax passes of v6). Swapped
// QK^T keeps softmax lane-local; defer-max (THR=8, P <= e^8 fits f16) skips
// the rescale+broadcast in the common case. LDS 80KB -> 2 blocks/CU.
__global__ __launch_bounds__(512, 4) void attn_kernel(
    const _Float16* __restrict__ q, const _Float16* __restrict__ kh,
    const _Float16* __restrict__ vt, _Float16* __restrict__ ao)
{
  __shared__ __align__(16) _Float16 Ks[2][128 * 64];  // 16 KB each
  __shared__ __align__(16) _Float16 Vs[2][64 * 128];  // 16 KB each
  __shared__ __align__(16) _Float16 P[8][16 * 64];    // 16 KB
  const int tid = threadIdx.x;
  const int lane = tid & 63, w = tid >> 6;
  const int l15 = lane & 15, lhi = lane >> 4;
  const int id = blockIdx.x;
  const int bh = id & 127, tb = id >> 7;
  const int b = bh >> 4, h = bh & 15;
  const int t0 = tb * 128 + w * 16;

  const _Float16* qp = q + (size_t)(b * TT + t0 + l15) * HID + h * DH + lhi * 8;
  half8 aq0 = *(const half8*)qp;
  half8 aq1 = *(const half8*)(qp + 32);

  const _Float16* kbase = kh + (size_t)(b * S_) * 1024 + h * DH;
  const _Float16* vbase = vt + (size_t)(h * DH) * 4096 + b * S_;

  // K chunk: 128 s-rows x 64 d. Per wave 2 gloads; row r = (w*2+i)*8+(l>>3),
  // chunk (l&7) ^ (r&7).
  auto stageK = [&](int c, int pg) {
    #pragma unroll
    for (int i = 0; i < 2; ++i) {
      const int r = (w * 2 + i) * 8 + (lane >> 3);
      const int sj = (lane & 7) ^ (r & 7);
      gload_lds16(kbase + (size_t)(c * 128 + r) * 1024 + sj * 8,
                  &Ks[pg][(w * 2 + i) * 512]);
    }
  };
  // V^T chunk: 64 d-rows x 128 s. Row r = (w*2+i)*4+(l>>4), 16B-chunk
  // (l&15) ^ (r&7).
  auto stageV = [&](int c, int pg) {
    #pragma unroll
    for (int i = 0; i < 2; ++i) {
      const int r = (w * 2 + i) * 4 + (lane >> 4);
      const int sj = (lane & 15) ^ (r & 7);
      gload_lds16(vbase + (size_t)r * 4096 + c * 128 + sj * 8,
                  &Vs[pg][(w * 2 + i) * 512]);
    }
  };

  f32x4 acco[4] = {};
  float m_ = -1e30f, l_ = 0.f;           // per-lane state for q = l15

  const int key = l15 & 7;
  const int ck0 = lhi ^ key;
  const int swr = key << 3;

  stageK(0, 0); stageV(0, 0);
  __syncthreads();
  int cur = 0;
  for (int c = 0; c < 4; ++c) {
    if (c + 1 < 4) { stageK(c + 1, cur ^ 1); stageV(c + 1, cur ^ 1); }
    // --- QK^T swapped: accs[n] rows s = n*16+l15 (n=0..7), col(l15)=q ---
    f32x4 accs[8] = {};
    __builtin_amdgcn_s_setprio(1);
    #pragma unroll
    for (int n = 0; n < 8; ++n) {
      const int row = n * 16 + l15;
      half8 kf0 = *(const half8*)&Ks[cur][row * 64 + ck0 * 8];
      half8 kf1 = *(const half8*)&Ks[cur][row * 64 + (ck0 ^ 4) * 8];
      accs[n] = __builtin_amdgcn_mfma_f32_16x16x32_f16(kf0, aq0, accs[n], 0, 0, 0);
      accs[n] = __builtin_amdgcn_mfma_f32_16x16x32_f16(kf1, aq1, accs[n], 0, 0, 0);
    }
    __builtin_amdgcn_s_setprio(0);
    // --- lane-local online softmax for q = l15 (32 s-values in-lane) ---
    float mx = -1e30f;
    #pragma unroll
    for (int n = 0; n < 8; ++n) {
      float cn = fmaxf(fmaxf(accs[n][0], accs[n][1]),
                       fmaxf(accs[n][2], accs[n][3]));
      mx = fmaxf(mx, cn);
    }
    mx = fmaxf(mx, __shfl_xor(mx, 16, 64));
    mx = fmaxf(mx, __shfl_xor(mx, 32, 64));
    if (!__all(mx <= m_ + 8.f)) {        // defer-max: rescale only if needed
      const float mnew = fmaxf(m_, mx);
      const float scale = __expf(m_ - mnew);
      m_ = mnew;
      l_ *= scale;
      #pragma unroll
      for (int r = 0; r < 4; ++r) {
        const float s_r = __shfl(scale, (lane >> 4) * 4 + r, 16);
        #pragma unroll
        for (int n = 0; n < 4; ++n) acco[n][r] *= s_r;
      }
    }
    float sm = 0.f;
    #pragma unroll
    for (int n = 0; n < 8; ++n) {
      #pragma unroll
      for (int r = 0; r < 4; ++r) {
        float e = __expf(accs[n][r] - m_);
        accs[n][r] = e;
        sm += e;
      }
    }
    sm += __shfl_xor(sm, 16, 64);
    sm += __shfl_xor(sm, 32, 64);
    l_ += sm;
    // --- two s-halves: P write (q=l15 row) then PV ---
    #pragma unroll
    for (int sh = 0; sh < 2; ++sh) {
      #pragma unroll
      for (int n = 0; n < 4; ++n) {
        const int na = sh * 4 + n;
        half4v pw;
        pw[0] = (_Float16)accs[na][0]; pw[1] = (_Float16)accs[na][1];
        pw[2] = (_Float16)accs[na][2]; pw[3] = (_Float16)accs[na][3];
        const int base = (n * 16 + lhi * 4) ^ swr;
        *(half4v*)&P[w][l15 * 64 + base] = pw;
      }
      __builtin_amdgcn_s_setprio(1);
      #pragma unroll
      for (int ks = 0; ks < 2; ++ks) {
        half8 ap = *(const half8*)&P[w][l15 * 64 + ((ks * 32 + lhi * 8) ^ swr)];
        #pragma unroll
        for (int n = 0; n < 4; ++n) {
          const int row = n * 16 + l15;
          const int chunk = sh * 8 + ks * 4 + lhi;
          half8 vf = *(const half8*)&Vs[cur][row * 128 + ((chunk ^ (row & 7)) * 8)];
          acco[n] = __builtin_amdgcn_mfma_f32_16x16x32_f16(ap, vf, acco[n], 0, 0, 0);
        }
      }
      __builtin_amdgcn_s_setprio(0);
    }
    __syncthreads();
    cur ^= 1;
  }
  // --- finalize: chunk-XOR staging (conflict-free read-back) ---
  const float inv = 1.0f / (l_ * 8.0f);
  #pragma unroll
  for (int r = 0; r < 4; ++r) {
    const float inv_r = __shfl(inv, (lane >> 4) * 4 + r, 16);
    const int qrow = lhi * 4 + r;
    const int kq = qrow & 7;
    #pragma unroll
    for (int n = 0; n < 4; ++n) {
      const int d = n * 16 + l15;
      P[w][qrow * 64 + (((d >> 3) ^ kq) * 8) + (d & 7)] =
          (_Float16)(acco[n][r] * inv_r);
    }
  }
  const int q2 = lane >> 2;
  const int kq2 = q2 & 7;
  const int g0 = ((lane & 3) * 2) ^ kq2;
  const int g1 = ((lane & 3) * 2 + 1) ^ kq2;
  half8 o0 = *(const half8*)&P[w][q2 * 64 + g0 * 8];
  half8 o1 = *(const half8*)&P[w][q2 * 64 + g1 * 8];
  _Float16* op = ao + (size_t)(b * TT + t0 + q2) * HID + h * DH + (lane & 3) * 16;
  *(half8*)op = o0;
  *(half8*)(op + 8) = o1;
}

extern "C" void kernel_launch(void* const* d_in, const int* in_sizes, int n_in,
                              void* d_out, int out_size, void* d_ws, size_t ws_size,
                              hipStream_t stream) {
  const float* x     = (const float*)d_in[0];
  const float* media = (const float*)d_in[1];
  // d_in[2] media_locations: unused (reference discards the mask)
  const float* Wq    = (const float*)d_in[3];
  const float* Wkv   = (const float*)d_in[4];
  const float* Wo    = (const float*)d_in[5];
  const float* gamma = (const float*)d_in[6];
  const float* beta  = (const float*)d_in[7];
  float* out = (float*)d_out;

  char* ws = (char*)d_ws;
  _Float16* xn     = (_Float16*)(ws);                    // 8192x2048 (32MB)
  _Float16* qh     = (_Float16*)(ws + 33554432);         // 8192x1024 (16MB)
  _Float16* kh     = (_Float16*)(ws + 50331648);         // 4096x1024 (8MB)
  _Float16* vth    = (_Float16*)(ws + 58720256);         // 1024x4096 (8MB)
  _Float16* aoh    = (_Float16*)(ws + 67108864);         // 8192x1024 (16MB)
  _Float16* mediah = (_Float16*)(ws + 83886080);         // 4096x1024 (8MB)
  _Float16* wqT    = (_Float16*)(ws + 92274688);         // 1024x2048 (4MB)
  _Float16* wkvT   = (_Float16*)(ws + 96468992);         // 2048x1024 (4MB)
  _Float16* woT    = (_Float16*)(ws + 100663296);        // 2048x1024 (4MB)

  prep<<<dim3(18432), dim3(256), 0, stream>>>(
      x, gamma, beta, xn, Wq, wqT, Wkv, wkvT, Wo, woT, media, mediah);
  gemm_qkv<<<dim3(1024), dim3(256), 0, stream>>>(xn, wqT, qh, mediah, wkvT, kh, vth);
  attn_kernel<<<dim3(1024), dim3(512), 0, stream>>>(qh, kh, vth, aoh);
  gemm_out<<<dim3(256), dim3(512), 0, stream>>>(aoh, woT, out);
}

// Round 13
// 171.910 us; speedup vs baseline: 1.0344x; 1.0012x over previous
//
#include <hip/hip_runtime.h>
#include <hip/hip_bf16.h>
#include <stdint.h>

#define B_     8
#define TT     1024
#define DIM_   2048
#define S_     512
#define H_     16
#define DH     64
#define HID    1024

typedef _Float16 half8 __attribute__((ext_vector_type(8)));
typedef _Float16 half4v __attribute__((ext_vector_type(4)));
typedef float f32x4 __attribute__((ext_vector_type(4)));

__device__ __forceinline__ void gload_lds16(const void* g, void* l) {
  __builtin_amdgcn_global_load_lds(
      (__attribute__((address_space(1))) unsigned int*)(uintptr_t)g,
      (__attribute__((address_space(3))) unsigned int*)l, 16, 0, 0);
}

#define MFMA16(afv, bfv, nh)                                                  \
  do {                                                                        \
    __builtin_amdgcn_s_setprio(1);                                            \
    _Pragma("unroll")                                                         \
    for (int m_ = 0; m_ < 8; ++m_) {                                          \
      acc[m_][(nh)*2]   = __builtin_amdgcn_mfma_f32_16x16x32_f16(             \
          afv[m_], bfv[0], acc[m_][(nh)*2], 0, 0, 0);                         \
      acc[m_][(nh)*2+1] = __builtin_amdgcn_mfma_f32_16x16x32_f16(             \
          afv[m_], bfv[1], acc[m_][(nh)*2+1], 0, 0, 0);                       \
    }                                                                         \
    __builtin_amdgcn_s_setprio(0);                                            \
  } while (0)

// ---------------- fused prep: LN+cast, 3 weight transposes, media cast -----
__device__ __forceinline__ void transpose_tile(
    const float* __restrict__ in, _Float16* __restrict__ out,
    int R, int C, int bx, int by, float (*t)[33])
{
  const int tid = threadIdx.x;
  const int tx = tid & 31, ty = tid >> 5;
  const int c0 = bx * 32, r0 = by * 32;
  #pragma unroll
  for (int i = 0; i < 32; i += 8)
    t[ty + i][tx] = in[(size_t)(r0 + ty + i) * C + c0 + tx];
  __syncthreads();
  #pragma unroll
  for (int i = 0; i < 32; i += 8)
    out[(size_t)(c0 + ty + i) * R + r0 + tx] = (_Float16)t[tx][ty + i];
}

__global__ __launch_bounds__(256) void prep(
    const float* __restrict__ x, const float* __restrict__ gamma,
    const float* __restrict__ beta, _Float16* __restrict__ xn,
    const float* __restrict__ Wq,  _Float16* __restrict__ wqT,
    const float* __restrict__ Wkv, _Float16* __restrict__ wkvT,
    const float* __restrict__ Wo,  _Float16* __restrict__ woT,
    const float* __restrict__ media, _Float16* __restrict__ mediah)
{
  __shared__ float t[32][33];
  const int id = blockIdx.x;
  const int tid = threadIdx.x;
  if (id < 8192) {
    const float* xr = x + (size_t)id * DIM_;
    float4 a = ((const float4*)xr)[tid * 2];
    float4 b = ((const float4*)xr)[tid * 2 + 1];
    float s1 = a.x + a.y + a.z + a.w + b.x + b.y + b.z + b.w;
    float s2 = a.x*a.x + a.y*a.y + a.z*a.z + a.w*a.w
             + b.x*b.x + b.y*b.y + b.z*b.z + b.w*b.w;
    #pragma unroll
    for (int d = 1; d < 64; d <<= 1) {
      s1 += __shfl_xor(s1, d, 64);
      s2 += __shfl_xor(s2, d, 64);
    }
    const int w = tid >> 6, lane = tid & 63;
    if (lane == 0) { t[0][w] = s1; t[0][4 + w] = s2; }
    __syncthreads();
    s1 = t[0][0] + t[0][1] + t[0][2] + t[0][3];
    s2 = t[0][4] + t[0][5] + t[0][6] + t[0][7];
    const float mu  = s1 * (1.0f / DIM_);
    const float var = s2 * (1.0f / DIM_) - mu * mu;
    const float rs  = rsqrtf(var + 1e-5f);
    float4 g0 = ((const float4*)gamma)[tid * 2];
    float4 g1 = ((const float4*)gamma)[tid * 2 + 1];
    float4 e0 = ((const float4*)beta)[tid * 2];
    float4 e1 = ((const float4*)beta)[tid * 2 + 1];
    half8 o;
    o[0] = (_Float16)((a.x - mu) * rs * g0.x + e0.x);
    o[1] = (_Float16)((a.y - mu) * rs * g0.y + e0.y);
    o[2] = (_Float16)((a.z - mu) * rs * g0.z + e0.z);
    o[3] = (_Float16)((a.w - mu) * rs * g0.w + e0.w);
    o[4] = (_Float16)((b.x - mu) * rs * g1.x + e1.x);
    o[5] = (_Float16)((b.y - mu) * rs * g1.y + e1.y);
    o[6] = (_Float16)((b.z - mu) * rs * g1.z + e1.z);
    o[7] = (_Float16)((b.w - mu) * rs * g1.w + e1.w);
    *(half8*)(xn + (size_t)id * DIM_ + tid * 8) = o;
  } else if (id < 10240) {
    const int lid = id - 8192;
    transpose_tile(Wq, wqT, 2048, 1024, lid & 31, lid >> 5, t);
  } else if (id < 12288) {
    const int lid = id - 10240;
    transpose_tile(Wkv, wkvT, 1024, 2048, lid & 63, lid >> 6, t);
  } else if (id < 14336) {
    const int lid = id - 12288;
    transpose_tile(Wo, woT, 1024, 2048, lid & 63, lid >> 6, t);
  } else {
    const int i = (id - 14336) * 256 + tid;
    float4 v = ((const float4*)media)[i];
    half4v o;
    o[0] = (_Float16)v.x; o[1] = (_Float16)v.y;
    o[2] = (_Float16)v.z; o[3] = (_Float16)v.w;
    ((half4v*)mediah)[i] = o;
  }
}

// ---------------- 128x128 GEMM, BK=32, 4 waves, m97-style loop -------------
template<typename OutT>
__device__ __forceinline__ void gemm128_body(
    const _Float16* __restrict__ A, const _Float16* __restrict__ BT,
    OutT* __restrict__ C, int KD, int ND, int m0, int n0,
    _Float16* __restrict__ sA, _Float16* __restrict__ sB)
{
  const int tid = threadIdx.x;
  const int lane = tid & 63, w = tid >> 6;
  const int l15 = lane & 15, lhi = lane >> 4;
  const int wr = w >> 1, wc = w & 1;
  const int rr = tid >> 2;
  const int sc = (tid & 3) ^ ((rr >> 1) & 3);

  auto stage = [&](const _Float16* __restrict__ G, int base, int k0,
                   _Float16* dst) {
    #pragma unroll
    for (int j = 0; j < 2; ++j) {
      const int r = j * 64 + rr;
      gload_lds16(G + (size_t)(base + r) * KD + k0 + sc * 8,
                  dst + j * 2048 + w * 512);
    }
  };

  f32x4 acc[4][4] = {};
  const int NT = KD >> 5;
  const int ck = lhi ^ ((l15 >> 1) & 3);

  stage(A, m0, 0, sA);
  stage(BT, n0, 0, sB);
  __syncthreads();
  int cur = 0;
  for (int kt = 0; kt < NT; ++kt) {
    if (kt + 1 < NT) {
      stage(A, m0, (kt + 1) * 32, sA + (cur ^ 1) * 4096);
      stage(BT, n0, (kt + 1) * 32, sB + (cur ^ 1) * 4096);
    }
    const _Float16* cA = sA + cur * 4096;
    const _Float16* cB = sB + cur * 4096;
    half8 af[4], bf[4];
    #pragma unroll
    for (int m = 0; m < 4; ++m)
      af[m] = *(const half8*)&cA[(wr * 64 + m * 16 + l15) * 32 + ck * 8];
    #pragma unroll
    for (int n = 0; n < 4; ++n)
      bf[n] = *(const half8*)&cB[(wc * 64 + n * 16 + l15) * 32 + ck * 8];
    #pragma unroll
    for (int m = 0; m < 4; ++m)
      #pragma unroll
      for (int n = 0; n < 4; ++n)
        acc[m][n] = __builtin_amdgcn_mfma_f32_16x16x32_f16(
            af[m], bf[n], acc[m][n], 0, 0, 0);
    __syncthreads();
    cur ^= 1;
  }

  #pragma unroll
  for (int m = 0; m < 4; ++m) {
    const int row = m0 + wr * 64 + m * 16 + lhi * 4;
    #pragma unroll
    for (int n = 0; n < 4; ++n) {
      const int col = n0 + wc * 64 + n * 16 + l15;
      #pragma unroll
      for (int r = 0; r < 4; ++r)
        C[(size_t)(row + r) * ND + col] = (OutT)acc[m][n][r];
    }
  }
}

// Fused Q + K + V^T: 512+256+256 = 1024 blocks = 4/CU.
__global__ __launch_bounds__(256, 4) void gemm_qkv(
    const _Float16* __restrict__ xn, const _Float16* __restrict__ wqT,
    _Float16* __restrict__ qh,
    const _Float16* __restrict__ mediah, const _Float16* __restrict__ wkvT,
    _Float16* __restrict__ kh, _Float16* __restrict__ vth)
{
  __shared__ __align__(16) _Float16 sA[2 * 4096], sB[2 * 4096];
  const int id = blockIdx.x;
  if (id < 512) {              // Q: M=8192 N=1024 K=2048
    const int m = id & 63, n = id >> 6;
    gemm128_body<_Float16>(xn, wqT, qh, 2048, 1024, m * 128, n * 128, sA, sB);
  } else if (id < 768) {       // K: M=4096 N=1024 K=1024
    const int lid = id - 512;
    const int m = lid & 31, n = lid >> 5;
    gemm128_body<_Float16>(mediah, wkvT, kh, 1024, 1024, m * 128, n * 128, sA, sB);
  } else {                     // V^T: M=1024 N=4096 K=1024
    const int lid = id - 768;
    const int m = lid & 7, n = lid >> 3;
    gemm128_body<_Float16>(wkvT + 1024 * 1024, mediah, vth, 1024, 4096,
                           m * 128, n * 128, sA, sB);
  }
}

// ---------------- 256x256 GEMM, BK=64, 8-phase counted-vmcnt (out-proj) ----
template<int KD, int ND, typename OutT>
__device__ __forceinline__ void gemm256_body(
    const _Float16* __restrict__ A, const _Float16* __restrict__ BT,
    OutT* __restrict__ C, int m0, int n0,
    _Float16* __restrict__ sAe, _Float16* __restrict__ sAo,
    _Float16* __restrict__ sBe, _Float16* __restrict__ sBo)
{
  constexpr int NT = KD / 64;
  constexpr int NI = NT / 2;
  const int tid = threadIdx.x;
  const int lane = tid & 63, w = tid >> 6;
  const int l15 = lane & 15, lhi = lane >> 4;
  const int wr = w >> 2, wc = w & 3;
  const int rs = l15 & 7;
  const int srow = tid >> 3;
  const int sch = (tid & 7) ^ (srow & 7);

  auto stage = [&](const _Float16* __restrict__ G, int base, int kt, int h,
                   _Float16* __restrict__ dst) {
    #pragma unroll
    for (int j = 0; j < 2; ++j) {
      const int r = h * 128 + j * 64 + srow;
      gload_lds16(G + (size_t)(base + r) * KD + kt * 64 + sch * 8,
                  dst + h * 8192 + j * 4096 + w * 512);
    }
  };

  f32x4 acc[8][4] = {};
  half8 af0[8], af1[8], bf0[2], bf1[2];

  stage(A,  m0, 0, 0, sAe); stage(A,  m0, 0, 1, sAe);
  stage(BT, n0, 0, 0, sBe); stage(BT, n0, 0, 1, sBe);
  stage(A,  m0, 1, 0, sAo); stage(A,  m0, 1, 1, sAo);
  asm volatile("s_waitcnt vmcnt(4)" ::: "memory");
  __builtin_amdgcn_s_barrier();

  for (int it = 0; it < NI; ++it) {
    const bool pf = (it + 1 < NI);
    const int t1 = 2 * it + 1, tn0 = 2 * it + 2, tn1 = 2 * it + 3;

    #pragma unroll
    for (int m = 0; m < 8; ++m)
      af0[m] = *(const half8*)&sAe[(wr*128 + m*16 + l15)*64 + ((lhi ^ rs)*8)];
    #pragma unroll
    for (int n = 0; n < 2; ++n)
      bf0[n] = *(const half8*)&sBe[(wc*64 + n*16 + l15)*64 + ((lhi ^ rs)*8)];
    stage(BT, n0, t1, 0, sBo);
    __builtin_amdgcn_s_barrier();
    asm volatile("s_waitcnt lgkmcnt(0)" ::: "memory");
    MFMA16(af0, bf0, 0);
    __builtin_amdgcn_s_barrier();
    #pragma unroll
    for (int m = 0; m < 8; ++m)
      af1[m] = *(const half8*)&sAe[(wr*128 + m*16 + l15)*64 + (((4+lhi) ^ rs)*8)];
    #pragma unroll
    for (int n = 0; n < 2; ++n)
      bf1[n] = *(const half8*)&sBe[(wc*64 + (2+n)*16 + l15)*64 + ((lhi ^ rs)*8)];
    stage(BT, n0, t1, 1, sBo);
    __builtin_amdgcn_s_barrier();
    asm volatile("s_waitcnt lgkmcnt(0)" ::: "memory");
    MFMA16(af0, bf1, 1);
    __builtin_amdgcn_s_barrier();
    #pragma unroll
    for (int n = 0; n < 2; ++n)
      bf0[n] = *(const half8*)&sBe[(wc*64 + n*16 + l15)*64 + (((4+lhi) ^ rs)*8)];
    if (pf) stage(A, m0, tn0, 0, sAe);
    __builtin_amdgcn_s_barrier();
    asm volatile("s_waitcnt lgkmcnt(0)" ::: "memory");
    MFMA16(af1, bf0, 0);
    __builtin_amdgcn_s_barrier();
    #pragma unroll
    for (int n = 0; n < 2; ++n)
      bf1[n] = *(const half8*)&sBe[(wc*64 + (2+n)*16 + l15)*64 + (((4+lhi) ^ rs)*8)];
    if (pf) stage(A, m0, tn0, 1, sAe);
    __builtin_amdgcn_s_barrier();
    asm volatile("s_waitcnt lgkmcnt(0)" ::: "memory");
    MFMA16(af1, bf1, 1);
    if (pf) asm volatile("s_waitcnt vmcnt(4)" ::: "memory");
    else    asm volatile("s_waitcnt vmcnt(0)" ::: "memory");
    __builtin_amdgcn_s_barrier();

    #pragma unroll
    for (int m = 0; m < 8; ++m)
      af0[m] = *(const half8*)&sAo[(wr*128 + m*16 + l15)*64 + ((lhi ^ rs)*8)];
    #pragma unroll
    for (int n = 0; n < 2; ++n)
      bf0[n] = *(const half8*)&sBo[(wc*64 + n*16 + l15)*64 + ((lhi ^ rs)*8)];
    if (pf) stage(BT, n0, tn0, 0, sBe);
    __builtin_amdgcn_s_barrier();
    asm volatile("s_waitcnt lgkmcnt(0)" ::: "memory");
    MFMA16(af0, bf0, 0);
    __builtin_amdgcn_s_barrier();
    #pragma unroll
    for (int m = 0; m < 8; ++m)
      af1[m] = *(const half8*)&sAo[(wr*128 + m*16 + l15)*64 + (((4+lhi) ^ rs)*8)];
    #pragma unroll
    for (int n = 0; n < 2; ++n)
      bf1[n] = *(const half8*)&sBo[(wc*64 + (2+n)*16 + l15)*64 + ((lhi ^ rs)*8)];
    if (pf) stage(BT, n0, tn0, 1, sBe);
    __builtin_amdgcn_s_barrier();
    asm volatile("s_waitcnt lgkmcnt(0)" ::: "memory");
    MFMA16(af0, bf1, 1);
    __builtin_amdgcn_s_barrier();
    #pragma unroll
    for (int n = 0; n < 2; ++n)
      bf0[n] = *(const half8*)&sBo[(wc*64 + n*16 + l15)*64 + (((4+lhi) ^ rs)*8)];
    if (pf) stage(A, m0, tn1, 0, sAo);
    __builtin_amdgcn_s_barrier();
    asm volatile("s_waitcnt lgkmcnt(0)" ::: "memory");
    MFMA16(af1, bf0, 0);
    __builtin_amdgcn_s_barrier();
    #pragma unroll
    for (int n = 0; n < 2; ++n)
      bf1[n] = *(const half8*)&sBo[(wc*64 + (2+n)*16 + l15)*64 + (((4+lhi) ^ rs)*8)];
    if (pf) stage(A, m0, tn1, 1, sAo);
    __builtin_amdgcn_s_barrier();
    asm volatile("s_waitcnt lgkmcnt(0)" ::: "memory");
    MFMA16(af1, bf1, 1);
    if (pf) asm volatile("s_waitcnt vmcnt(4)" ::: "memory");
    else    asm volatile("s_waitcnt vmcnt(0)" ::: "memory");
    __builtin_amdgcn_s_barrier();
  }

  #pragma unroll
  for (int mf = 0; mf < 8; ++mf) {
    const int row = m0 + wr * 128 + mf * 16 + lhi * 4;
    #pragma unroll
    for (int nf = 0; nf < 4; ++nf) {
      const int col = n0 + wc * 64 + nf * 16 + l15;
      #pragma unroll
      for (int r = 0; r < 4; ++r)
        C[(size_t)(row + r) * ND + col] = (OutT)acc[mf][nf][r];
    }
  }
}

__global__ __launch_bounds__(512, 2) void gemm_out(
    const _Float16* __restrict__ aoh, const _Float16* __restrict__ woT,
    float* __restrict__ out)
{
  __shared__ __align__(16) _Float16 sAe[256 * 64], sAo[256 * 64];
  __shared__ __align__(16) _Float16 sBe[256 * 64], sBo[256 * 64];
  const int id = blockIdx.x;
  const int m = id & 31, n = id >> 5;
  gemm256_body<1024, 2048, float>(aoh, woT, out, m * 256, n * 256,
                                  sAe, sAo, sBe, sBo);
}

// ---------------- fused attention v8: whole-KV in LDS, single-pass softmax -
// Grid 256 = (qhalf, b, h): id = qhalf*128 + bh -> both q-halves of a (b,h)
// on one XCD. Stage K[512][64] + V^T[64][512] ONCE (144KB LDS, 1 block/CU,
// no tail). vmcnt(8) gates K; one-time vmcnt(0)+barrier before first PV
// hides V staging under QK0+softmax0. Then 4 iters x 16 q-rows/wave:
// full-S swapped QK^T (128 scores/lane) -> single-pass exact softmax (tree
// max/sum + 2 shfl, no online state) -> P normalized at write -> PV over 8
// wave-private chunks. ZERO barriers in the main loop.
__global__ __launch_bounds__(512, 2) void attn_kernel(
    const _Float16* __restrict__ q, const _Float16* __restrict__ kh,
    const _Float16* __restrict__ vt, _Float16* __restrict__ ao)
{
  __shared__ __align__(16) _Float16 Ks[512 * 64];   // 64 KB
  __shared__ __align__(16) _Float16 Vs[64 * 512];   // 64 KB
  __shared__ __align__(16) _Float16 P[8][16 * 64];  // 16 KB
  const int tid = threadIdx.x;
  const int lane = tid & 63, w = tid >> 6;
  const int l15 = lane & 15, lhi = lane >> 4;
  const int id = blockIdx.x;
  const int bh = id & 127, qhalf = id >> 7;
  const int b = bh >> 4, h = bh & 15;

  const _Float16* kbase = kh + (size_t)(b * S_) * 1024 + h * DH;
  const _Float16* vbase = vt + (size_t)(h * DH) * 4096 + b * S_;

  // ---- one-shot staging: K first (8 gloads/thread), then V (8/thread) ----
  {
    const int kr = w * 8 + (lane >> 3);          // K row within 64-row round
    const int kc = (lane & 7) ^ (lane >> 3);     // pre-swizzled source chunk
    #pragma unroll
    for (int j = 0; j < 8; ++j)
      gload_lds16(kbase + (size_t)(j * 64 + kr) * 1024 + kc * 8,
                  &Ks[(j * 64 + w * 8) * 64]);
    const int vc = lane ^ (w & 7);               // V source chunk (row&7 == w)
    #pragma unroll
    for (int j = 0; j < 8; ++j)
      gload_lds16(vbase + (size_t)(j * 8 + w) * 4096 + vc * 8,
                  &Vs[(j * 8 + w) * 512]);
  }
  asm volatile("s_waitcnt vmcnt(8)" ::: "memory");   // K resident
  __syncthreads();

  const int key = l15 & 7;
  const int ck0 = lhi ^ key, ck1 = (4 + lhi) ^ key;
  const int swr = key << 3;

  const _Float16* qp0 = q + (size_t)(b * TT + qhalf * 512 + w * 16 + l15) * HID
                        + h * DH + lhi * 8;
  half8 aq0 = *(const half8*)qp0;
  half8 aq1 = *(const half8*)(qp0 + 32);

  for (int it = 0; it < 4; ++it) {
    const int t0 = qhalf * 512 + it * 128 + w * 16;
    // --- QK^T swapped over full S: accs[n] rows s=n*16+l15, col(l15)=q ---
    f32x4 accs[32] = {};
    __builtin_amdgcn_s_setprio(1);
    #pragma unroll
    for (int n = 0; n < 32; ++n) {
      const int row = n * 16 + l15;
      half8 kf0 = *(const half8*)&Ks[row * 64 + ck0 * 8];
      half8 kf1 = *(const half8*)&Ks[row * 64 + ck1 * 8];
      accs[n] = __builtin_amdgcn_mfma_f32_16x16x32_f16(kf0, aq0, accs[n], 0, 0, 0);
      accs[n] = __builtin_amdgcn_mfma_f32_16x16x32_f16(kf1, aq1, accs[n], 0, 0, 0);
    }
    __builtin_amdgcn_s_setprio(0);
    // --- single-pass softmax for q = l15 (128 in-lane values) ---
    float g[8];
    #pragma unroll
    for (int k = 0; k < 8; ++k) {
      float m0 = fmaxf(fmaxf(accs[4*k+0][0], accs[4*k+0][1]),
                       fmaxf(accs[4*k+0][2], accs[4*k+0][3]));
      float m1 = fmaxf(fmaxf(accs[4*k+1][0], accs[4*k+1][1]),
                       fmaxf(accs[4*k+1][2], accs[4*k+1][3]));
      float m2 = fmaxf(fmaxf(accs[4*k+2][0], accs[4*k+2][1]),
                       fmaxf(accs[4*k+2][2], accs[4*k+2][3]));
      float m3 = fmaxf(fmaxf(accs[4*k+3][0], accs[4*k+3][1]),
                       fmaxf(accs[4*k+3][2], accs[4*k+3][3]));
      g[k] = fmaxf(fmaxf(m0, m1), fmaxf(m2, m3));
    }
    float mx = fmaxf(fmaxf(fmaxf(g[0], g[1]), fmaxf(g[2], g[3])),
                     fmaxf(fmaxf(g[4], g[5]), fmaxf(g[6], g[7])));
    mx = fmaxf(mx, __shfl_xor(mx, 16, 64));
    mx = fmaxf(mx, __shfl_xor(mx, 32, 64));
    float sg[8];
    #pragma unroll
    for (int k = 0; k < 8; ++k) {
      float s = 0.f;
      #pragma unroll
      for (int j = 0; j < 4; ++j) {
        const int n = 4 * k + j;
        #pragma unroll
        for (int r = 0; r < 4; ++r) {
          float e = __expf(accs[n][r] - mx);
          accs[n][r] = e;
          s += e;
        }
      }
      sg[k] = s;
    }
    float sm = ((sg[0]+sg[1]) + (sg[2]+sg[3])) + ((sg[4]+sg[5]) + (sg[6]+sg[7]));
    sm += __shfl_xor(sm, 16, 64);
    sm += __shfl_xor(sm, 32, 64);
    const float inv = 1.0f / (sm * 8.0f);   // softmax then /sqrt(DH), folded
    // --- prefetch next iter's Q fragments ---
    half8 aqn0, aqn1;
    if (it < 3) {
      const _Float16* qp = q + (size_t)(b * TT + t0 + 128 + l15) * HID
                           + h * DH + lhi * 8;
      aqn0 = *(const half8*)qp;
      aqn1 = *(const half8*)(qp + 32);
    }
    // --- one-time gate: V resident before first PV ---
    if (it == 0) {
      asm volatile("s_waitcnt vmcnt(0)" ::: "memory");
      __builtin_amdgcn_s_barrier();
    }
    // --- PV over 8 wave-private s-chunks of 64 ---
    f32x4 acco[4] = {};
    #pragma unroll
    for (int c = 0; c < 8; ++c) {
      #pragma unroll
      for (int n = 0; n < 4; ++n) {
        const int na = c * 4 + n;
        half4v pw;
        pw[0] = (_Float16)(accs[na][0] * inv);
        pw[1] = (_Float16)(accs[na][1] * inv);
        pw[2] = (_Float16)(accs[na][2] * inv);
        pw[3] = (_Float16)(accs[na][3] * inv);
        const int base = (n * 16 + lhi * 4) ^ swr;
        *(half4v*)&P[w][l15 * 64 + base] = pw;
      }
      __builtin_amdgcn_s_setprio(1);
      #pragma unroll
      for (int ks = 0; ks < 2; ++ks) {
        half8 ap = *(const half8*)&P[w][l15 * 64 + ((ks * 32 + lhi * 8) ^ swr)];
        #pragma unroll
        for (int n = 0; n < 4; ++n) {
          const int row = n * 16 + l15;
          const int sidx = c * 8 + ks * 4 + lhi;      // 16B chunk in V row
          half8 vf = *(const half8*)&Vs[row * 512 + ((sidx ^ (row & 7)) * 8)];
          acco[n] = __builtin_amdgcn_mfma_f32_16x16x32_f16(ap, vf, acco[n], 0, 0, 0);
        }
      }
      __builtin_amdgcn_s_setprio(0);
    }
    // --- epilogue: stage to P (wave-private), coalesced 16B stores ---
    #pragma unroll
    for (int r = 0; r < 4; ++r) {
      const int qrow = lhi * 4 + r;
      const int kq = qrow & 7;
      #pragma unroll
      for (int n = 0; n < 4; ++n) {
        const int d = n * 16 + l15;
        P[w][qrow * 64 + (((d >> 3) ^ kq) * 8) + (d & 7)] = (_Float16)acco[n][r];
      }
    }
    const int q2 = lane >> 2;
    const int kq2 = q2 & 7;
    const int g0i = ((lane & 3) * 2) ^ kq2;
    const int g1i = ((lane & 3) * 2 + 1) ^ kq2;
    half8 o0 = *(const half8*)&P[w][q2 * 64 + g0i * 8];
    half8 o1 = *(const half8*)&P[w][q2 * 64 + g1i * 8];
    _Float16* op = ao + (size_t)(b * TT + t0 + q2) * HID + h * DH + (lane & 3) * 16;
    *(half8*)op = o0;
    *(half8*)(op + 8) = o1;
    aq0 = aqn0;
    aq1 = aqn1;
  }
}

extern "C" void kernel_launch(void* const* d_in, const int* in_sizes, int n_in,
                              void* d_out, int out_size, void* d_ws, size_t ws_size,
                              hipStream_t stream) {
  const float* x     = (const float*)d_in[0];
  const float* media = (const float*)d_in[1];
  // d_in[2] media_locations: unused (reference discards the mask)
  const float* Wq    = (const float*)d_in[3];
  const float* Wkv   = (const float*)d_in[4];
  const float* Wo    = (const float*)d_in[5];
  const float* gamma = (const float*)d_in[6];
  const float* beta  = (const float*)d_in[7];
  float* out = (float*)d_out;

  char* ws = (char*)d_ws;
  _Float16* xn     = (_Float16*)(ws);                    // 8192x2048 (32MB)
  _Float16* qh     = (_Float16*)(ws + 33554432);         // 8192x1024 (16MB)
  _Float16* kh     = (_Float16*)(ws + 50331648);         // 4096x1024 (8MB)
  _Float16* vth    = (_Float16*)(ws + 58720256);         // 1024x4096 (8MB)
  _Float16* aoh    = (_Float16*)(ws + 67108864);         // 8192x1024 (16MB)
  _Float16* mediah = (_Float16*)(ws + 83886080);         // 4096x1024 (8MB)
  _Float16* wqT    = (_Float16*)(ws + 92274688);         // 1024x2048 (4MB)
  _Float16* wkvT   = (_Float16*)(ws + 96468992);         // 2048x1024 (4MB)
  _Float16* woT    = (_Float16*)(ws + 100663296);        // 2048x1024 (4MB)

  prep<<<dim3(18432), dim3(256), 0, stream>>>(
      x, gamma, beta, xn, Wq, wqT, Wkv, wkvT, Wo, woT, media, mediah);
  gemm_qkv<<<dim3(1024), dim3(256), 0, stream>>>(xn, wqT, qh, mediah, wkvT, kh, vth);
  attn_kernel<<<dim3(256), dim3(512), 0, stream>>>(qh, kh, vth, aoh);
  gemm_out<<<dim3(256), dim3(512), 0, stream>>>(aoh, woT, out);
}

// Round 16
// 169.438 us; speedup vs baseline: 1.0495x; 1.0146x over previous
//
#include <hip/hip_runtime.h>
#include <hip/hip_bf16.h>
#include <stdint.h>

#define B_     8
#define TT     1024
#define DIM_   2048
#define S_     512
#define H_     16
#define DH     64
#define HID    1024

typedef _Float16 half8 __attribute__((ext_vector_type(8)));
typedef _Float16 half4v __attribute__((ext_vector_type(4)));
typedef float f32x4 __attribute__((ext_vector_type(4)));
typedef float f32x16 __attribute__((ext_vector_type(16)));

__device__ __forceinline__ void gload_lds16(const void* g, void* l) {
  __builtin_amdgcn_global_load_lds(
      (__attribute__((address_space(1))) unsigned int*)(uintptr_t)g,
      (__attribute__((address_space(3))) unsigned int*)l, 16, 0, 0);
}

__device__ __forceinline__ unsigned int pkrtz(float a, float b) {
  auto h = __builtin_amdgcn_cvt_pkrtz(a, b);   // __fp16 ext_vector(2)
  return __builtin_bit_cast(unsigned int, h);
}

#define MFMA16(afv, bfv, nh)                                                  \
  do {                                                                        \
    __builtin_amdgcn_s_setprio(1);                                            \
    _Pragma("unroll")                                                         \
    for (int m_ = 0; m_ < 8; ++m_) {                                          \
      acc[m_][(nh)*2]   = __builtin_amdgcn_mfma_f32_16x16x32_f16(             \
          afv[m_], bfv[0], acc[m_][(nh)*2], 0, 0, 0);                         \
      acc[m_][(nh)*2+1] = __builtin_amdgcn_mfma_f32_16x16x32_f16(             \
          afv[m_], bfv[1], acc[m_][(nh)*2+1], 0, 0, 0);                       \
    }                                                                         \
    __builtin_amdgcn_s_setprio(0);                                            \
  } while (0)

// ---------------- fused prep: LN+cast, 3 weight transposes, media cast -----
__device__ __forceinline__ void transpose_tile(
    const float* __restrict__ in, _Float16* __restrict__ out,
    int R, int C, int bx, int by, float (*t)[33])
{
  const int tid = threadIdx.x;
  const int tx = tid & 31, ty = tid >> 5;
  const int c0 = bx * 32, r0 = by * 32;
  #pragma unroll
  for (int i = 0; i < 32; i += 8)
    t[ty + i][tx] = in[(size_t)(r0 + ty + i) * C + c0 + tx];
  __syncthreads();
  #pragma unroll
  for (int i = 0; i < 32; i += 8)
    out[(size_t)(c0 + ty + i) * R + r0 + tx] = (_Float16)t[tx][ty + i];
}

__global__ __launch_bounds__(256) void prep(
    const float* __restrict__ x, const float* __restrict__ gamma,
    const float* __restrict__ beta, _Float16* __restrict__ xn,
    const float* __restrict__ Wq,  _Float16* __restrict__ wqT,
    const float* __restrict__ Wkv, _Float16* __restrict__ wkvT,
    const float* __restrict__ Wo,  _Float16* __restrict__ woT,
    const float* __restrict__ media, _Float16* __restrict__ mediah)
{
  __shared__ float t[32][33];
  const int id = blockIdx.x;
  const int tid = threadIdx.x;
  if (id < 8192) {
    const float* xr = x + (size_t)id * DIM_;
    float4 a = ((const float4*)xr)[tid * 2];
    float4 b = ((const float4*)xr)[tid * 2 + 1];
    float s1 = a.x + a.y + a.z + a.w + b.x + b.y + b.z + b.w;
    float s2 = a.x*a.x + a.y*a.y + a.z*a.z + a.w*a.w
             + b.x*b.x + b.y*b.y + b.z*b.z + b.w*b.w;
    #pragma unroll
    for (int d = 1; d < 64; d <<= 1) {
      s1 += __shfl_xor(s1, d, 64);
      s2 += __shfl_xor(s2, d, 64);
    }
    const int w = tid >> 6, lane = tid & 63;
    if (lane == 0) { t[0][w] = s1; t[0][4 + w] = s2; }
    __syncthreads();
    s1 = t[0][0] + t[0][1] + t[0][2] + t[0][3];
    s2 = t[0][4] + t[0][5] + t[0][6] + t[0][7];
    const float mu  = s1 * (1.0f / DIM_);
    const float var = s2 * (1.0f / DIM_) - mu * mu;
    const float rs  = rsqrtf(var + 1e-5f);
    float4 g0 = ((const float4*)gamma)[tid * 2];
    float4 g1 = ((const float4*)gamma)[tid * 2 + 1];
    float4 e0 = ((const float4*)beta)[tid * 2];
    float4 e1 = ((const float4*)beta)[tid * 2 + 1];
    half8 o;
    o[0] = (_Float16)((a.x - mu) * rs * g0.x + e0.x);
    o[1] = (_Float16)((a.y - mu) * rs * g0.y + e0.y);
    o[2] = (_Float16)((a.z - mu) * rs * g0.z + e0.z);
    o[3] = (_Float16)((a.w - mu) * rs * g0.w + e0.w);
    o[4] = (_Float16)((b.x - mu) * rs * g1.x + e1.x);
    o[5] = (_Float16)((b.y - mu) * rs * g1.y + e1.y);
    o[6] = (_Float16)((b.z - mu) * rs * g1.z + e1.z);
    o[7] = (_Float16)((b.w - mu) * rs * g1.w + e1.w);
    *(half8*)(xn + (size_t)id * DIM_ + tid * 8) = o;
  } else if (id < 10240) {
    const int lid = id - 8192;
    transpose_tile(Wq, wqT, 2048, 1024, lid & 31, lid >> 5, t);
  } else if (id < 12288) {
    const int lid = id - 10240;
    transpose_tile(Wkv, wkvT, 1024, 2048, lid & 63, lid >> 6, t);
  } else if (id < 14336) {
    const int lid = id - 12288;
    transpose_tile(Wo, woT, 1024, 2048, lid & 63, lid >> 6, t);
  } else {
    const int i = (id - 14336) * 256 + tid;
    float4 v = ((const float4*)media)[i];
    half4v o;
    o[0] = (_Float16)v.x; o[1] = (_Float16)v.y;
    o[2] = (_Float16)v.z; o[3] = (_Float16)v.w;
    ((half4v*)mediah)[i] = o;
  }
}

// ---------------- 128x128 GEMM, BK=32, 4 waves, m97-style loop -------------
template<typename OutT>
__device__ __forceinline__ void gemm128_body(
    const _Float16* __restrict__ A, const _Float16* __restrict__ BT,
    OutT* __restrict__ C, int KD, int ND, int m0, int n0,
    _Float16* __restrict__ sA, _Float16* __restrict__ sB)
{
  const int tid = threadIdx.x;
  const int lane = tid & 63, w = tid >> 6;
  const int l15 = lane & 15, lhi = lane >> 4;
  const int wr = w >> 1, wc = w & 1;
  const int rr = tid >> 2;
  const int sc = (tid & 3) ^ ((rr >> 1) & 3);

  auto stage = [&](const _Float16* __restrict__ G, int base, int k0,
                   _Float16* dst) {
    #pragma unroll
    for (int j = 0; j < 2; ++j) {
      const int r = j * 64 + rr;
      gload_lds16(G + (size_t)(base + r) * KD + k0 + sc * 8,
                  dst + j * 2048 + w * 512);
    }
  };

  f32x4 acc[4][4] = {};
  const int NT = KD >> 5;
  const int ck = lhi ^ ((l15 >> 1) & 3);

  stage(A, m0, 0, sA);
  stage(BT, n0, 0, sB);
  __syncthreads();
  int cur = 0;
  for (int kt = 0; kt < NT; ++kt) {
    if (kt + 1 < NT) {
      stage(A, m0, (kt + 1) * 32, sA + (cur ^ 1) * 4096);
      stage(BT, n0, (kt + 1) * 32, sB + (cur ^ 1) * 4096);
    }
    const _Float16* cA = sA + cur * 4096;
    const _Float16* cB = sB + cur * 4096;
    half8 af[4], bf[4];
    #pragma unroll
    for (int m = 0; m < 4; ++m)
      af[m] = *(const half8*)&cA[(wr * 64 + m * 16 + l15) * 32 + ck * 8];
    #pragma unroll
    for (int n = 0; n < 4; ++n)
      bf[n] = *(const half8*)&cB[(wc * 64 + n * 16 + l15) * 32 + ck * 8];
    #pragma unroll
    for (int m = 0; m < 4; ++m)
      #pragma unroll
      for (int n = 0; n < 4; ++n)
        acc[m][n] = __builtin_amdgcn_mfma_f32_16x16x32_f16(
            af[m], bf[n], acc[m][n], 0, 0, 0);
    __syncthreads();
    cur ^= 1;
  }

  #pragma unroll
  for (int m = 0; m < 4; ++m) {
    const int row = m0 + wr * 64 + m * 16 + lhi * 4;
    #pragma unroll
    for (int n = 0; n < 4; ++n) {
      const int col = n0 + wc * 64 + n * 16 + l15;
      #pragma unroll
      for (int r = 0; r < 4; ++r)
        C[(size_t)(row + r) * ND + col] = (OutT)acc[m][n][r];
    }
  }
}

// Fused Q + K + V^T: 512+256+256 = 1024 blocks = 4/CU.
__global__ __launch_bounds__(256, 4) void gemm_qkv(
    const _Float16* __restrict__ xn, const _Float16* __restrict__ wqT,
    _Float16* __restrict__ qh,
    const _Float16* __restrict__ mediah, const _Float16* __restrict__ wkvT,
    _Float16* __restrict__ kmat, _Float16* __restrict__ vth)
{
  __shared__ __align__(16) _Float16 sA[2 * 4096], sB[2 * 4096];
  const int id = blockIdx.x;
  if (id < 512) {              // Q: M=8192 N=1024 K=2048
    const int m = id & 63, n = id >> 6;
    gemm128_body<_Float16>(xn, wqT, qh, 2048, 1024, m * 128, n * 128, sA, sB);
  } else if (id < 768) {       // K: M=4096 N=1024 K=1024
    const int lid = id - 512;
    const int m = lid & 31, n = lid >> 5;
    gemm128_body<_Float16>(mediah, wkvT, kmat, 1024, 1024, m * 128, n * 128, sA, sB);
  } else {                     // V^T: M=1024 N=4096 K=1024
    const int lid = id - 768;
    const int m = lid & 7, n = lid >> 3;
    gemm128_body<_Float16>(wkvT + 1024 * 1024, mediah, vth, 1024, 4096,
                           m * 128, n * 128, sA, sB);
  }
}

// ---------------- 256x256 GEMM, BK=64, 8-phase counted-vmcnt (out-proj) ----
template<int KD, int ND, typename OutT>
__device__ __forceinline__ void gemm256_body(
    const _Float16* __restrict__ A, const _Float16* __restrict__ BT,
    OutT* __restrict__ C, int m0, int n0,
    _Float16* __restrict__ sAe, _Float16* __restrict__ sAo,
    _Float16* __restrict__ sBe, _Float16* __restrict__ sBo)
{
  constexpr int NT = KD / 64;
  constexpr int NI = NT / 2;
  const int tid = threadIdx.x;
  const int lane = tid & 63, w = tid >> 6;
  const int l15 = lane & 15, lhi = lane >> 4;
  const int wr = w >> 2, wc = w & 3;
  const int rs = l15 & 7;
  const int srow = tid >> 3;
  const int sch = (tid & 7) ^ (srow & 7);

  auto stage = [&](const _Float16* __restrict__ G, int base, int kt, int h,
                   _Float16* __restrict__ dst) {
    #pragma unroll
    for (int j = 0; j < 2; ++j) {
      const int r = h * 128 + j * 64 + srow;
      gload_lds16(G + (size_t)(base + r) * KD + kt * 64 + sch * 8,
                  dst + h * 8192 + j * 4096 + w * 512);
    }
  };

  f32x4 acc[8][4] = {};
  half8 af0[8], af1[8], bf0[2], bf1[2];

  stage(A,  m0, 0, 0, sAe); stage(A,  m0, 0, 1, sAe);
  stage(BT, n0, 0, 0, sBe); stage(BT, n0, 0, 1, sBe);
  stage(A,  m0, 1, 0, sAo); stage(A,  m0, 1, 1, sAo);
  asm volatile("s_waitcnt vmcnt(4)" ::: "memory");
  __builtin_amdgcn_s_barrier();

  for (int it = 0; it < NI; ++it) {
    const bool pf = (it + 1 < NI);
    const int t1 = 2 * it + 1, tn0 = 2 * it + 2, tn1 = 2 * it + 3;

    #pragma unroll
    for (int m = 0; m < 8; ++m)
      af0[m] = *(const half8*)&sAe[(wr*128 + m*16 + l15)*64 + ((lhi ^ rs)*8)];
    #pragma unroll
    for (int n = 0; n < 2; ++n)
      bf0[n] = *(const half8*)&sBe[(wc*64 + n*16 + l15)*64 + ((lhi ^ rs)*8)];
    stage(BT, n0, t1, 0, sBo);
    __builtin_amdgcn_s_barrier();
    asm volatile("s_waitcnt lgkmcnt(0)" ::: "memory");
    MFMA16(af0, bf0, 0);
    __builtin_amdgcn_s_barrier();
    #pragma unroll
    for (int m = 0; m < 8; ++m)
      af1[m] = *(const half8*)&sAe[(wr*128 + m*16 + l15)*64 + (((4+lhi) ^ rs)*8)];
    #pragma unroll
    for (int n = 0; n < 2; ++n)
      bf1[n] = *(const half8*)&sBe[(wc*64 + (2+n)*16 + l15)*64 + ((lhi ^ rs)*8)];
    stage(BT, n0, t1, 1, sBo);
    __builtin_amdgcn_s_barrier();
    asm volatile("s_waitcnt lgkmcnt(0)" ::: "memory");
    MFMA16(af0, bf1, 1);
    __builtin_amdgcn_s_barrier();
    #pragma unroll
    for (int n = 0; n < 2; ++n)
      bf0[n] = *(const half8*)&sBe[(wc*64 + n*16 + l15)*64 + (((4+lhi) ^ rs)*8)];
    if (pf) stage(A, m0, tn0, 0, sAe);
    __builtin_amdgcn_s_barrier();
    asm volatile("s_waitcnt lgkmcnt(0)" ::: "memory");
    MFMA16(af1, bf0, 0);
    __builtin_amdgcn_s_barrier();
    #pragma unroll
    for (int n = 0; n < 2; ++n)
      bf1[n] = *(const half8*)&sBe[(wc*64 + (2+n)*16 + l15)*64 + (((4+lhi) ^ rs)*8)];
    if (pf) stage(A, m0, tn0, 1, sAe);
    __builtin_amdgcn_s_barrier();
    asm volatile("s_waitcnt lgkmcnt(0)" ::: "memory");
    MFMA16(af1, bf1, 1);
    if (pf) asm volatile("s_waitcnt vmcnt(4)" ::: "memory");
    else    asm volatile("s_waitcnt vmcnt(0)" ::: "memory");
    __builtin_amdgcn_s_barrier();

    #pragma unroll
    for (int m = 0; m < 8; ++m)
      af0[m] = *(const half8*)&sAo[(wr*128 + m*16 + l15)*64 + ((lhi ^ rs)*8)];
    #pragma unroll
    for (int n = 0; n < 2; ++n)
      bf0[n] = *(const half8*)&sBo[(wc*64 + n*16 + l15)*64 + ((lhi ^ rs)*8)];
    if (pf) stage(BT, n0, tn0, 0, sBe);
    __builtin_amdgcn_s_barrier();
    asm volatile("s_waitcnt lgkmcnt(0)" ::: "memory");
    MFMA16(af0, bf0, 0);
    __builtin_amdgcn_s_barrier();
    #pragma unroll
    for (int m = 0; m < 8; ++m)
      af1[m] = *(const half8*)&sAo[(wr*128 + m*16 + l15)*64 + (((4+lhi) ^ rs)*8)];
    #pragma unroll
    for (int n = 0; n < 2; ++n)
      bf1[n] = *(const half8*)&sBo[(wc*64 + (2+n)*16 + l15)*64 + ((lhi ^ rs)*8)];
    if (pf) stage(BT, n0, tn0, 1, sBe);
    __builtin_amdgcn_s_barrier();
    asm volatile("s_waitcnt lgkmcnt(0)" ::: "memory");
    MFMA16(af0, bf1, 1);
    __builtin_amdgcn_s_barrier();
    #pragma unroll
    for (int n = 0; n < 2; ++n)
      bf0[n] = *(const half8*)&sBo[(wc*64 + n*16 + l15)*64 + (((4+lhi) ^ rs)*8)];
    if (pf) stage(A, m0, tn1, 0, sAo);
    __builtin_amdgcn_s_barrier();
    asm volatile("s_waitcnt lgkmcnt(0)" ::: "memory");
    MFMA16(af1, bf0, 0);
    __builtin_amdgcn_s_barrier();
    #pragma unroll
    for (int n = 0; n < 2; ++n)
      bf1[n] = *(const half8*)&sBo[(wc*64 + (2+n)*16 + l15)*64 + (((4+lhi) ^ rs)*8)];
    if (pf) stage(A, m0, tn1, 1, sAo);
    __builtin_amdgcn_s_barrier();
    asm volatile("s_waitcnt lgkmcnt(0)" ::: "memory");
    MFMA16(af1, bf1, 1);
    if (pf) asm volatile("s_waitcnt vmcnt(4)" ::: "memory");
    else    asm volatile("s_waitcnt vmcnt(0)" ::: "memory");
    __builtin_amdgcn_s_barrier();
  }

  #pragma unroll
  for (int mf = 0; mf < 8; ++mf) {
    const int row = m0 + wr * 128 + mf * 16 + lhi * 4;
    #pragma unroll
    for (int nf = 0; nf < 4; ++nf) {
      const int col = n0 + wc * 64 + nf * 16 + l15;
      #pragma unroll
      for (int r = 0; r < 4; ++r)
        C[(size_t)(row + r) * ND + col] = (OutT)acc[mf][nf][r];
    }
  }
}

__global__ __launch_bounds__(512, 2) void gemm_out(
    const _Float16* __restrict__ aoh, const _Float16* __restrict__ woT,
    float* __restrict__ out)
{
  __shared__ __align__(16) _Float16 sAe[256 * 64], sAo[256 * 64];
  __shared__ __align__(16) _Float16 sBe[256 * 64], sBo[256 * 64];
  const int id = blockIdx.x;
  const int m = id & 31, n = id >> 5;
  gemm256_body<1024, 2048, float>(aoh, woT, out, m * 256, n * 256,
                                  sAe, sAo, sBe, sBo);
}

// ---------------- fused attention v9b: 32x32x16 MFMA, in-register P --------
// v9 + the missing __syncthreads() before the output-staging epilogue (waves
// 4-7 stage their outputs into the Vs[1] region, which laggard waves were
// still PV-reading -> cross-wave race, absmax 5.4e-2).
__global__ __launch_bounds__(512, 2) void attn_kernel(
    const _Float16* __restrict__ q, const _Float16* __restrict__ kmat,
    const _Float16* __restrict__ vt, _Float16* __restrict__ ao)
{
  __shared__ __align__(16) _Float16 Ks[2][128 * 64];  // 16 KB each
  __shared__ __align__(16) _Float16 Vs[2][64 * 128];  // 16 KB each
  const int tid = threadIdx.x;
  const int lane = tid & 63, w = tid >> 6;
  const int l31 = lane & 31, g = lane >> 5;
  const int key = l31 & 7;
  const int id = blockIdx.x;
  const int bh = id & 127, qq = id >> 7;
  const int b = bh >> 4, h = bh & 15;
  const int qrow0 = qq * 256 + w * 32;

  const _Float16* kbase = kmat + (size_t)(b * S_) * 1024 + h * DH;
  const _Float16* vbase = vt + (size_t)(h * DH) * 4096 + b * S_;

  auto stageK = [&](int c, int pg) {
    #pragma unroll
    for (int j = 0; j < 2; ++j) {
      const int r = j * 64 + w * 8 + (lane >> 3);
      const int sj = (lane & 7) ^ (r & 7);
      gload_lds16(kbase + (size_t)(c * 128 + r) * 1024 + sj * 8,
                  &Ks[pg][(j * 64 + w * 8) * 64]);
    }
  };
  auto stageV = [&](int c, int pg) {
    #pragma unroll
    for (int j = 0; j < 2; ++j) {
      const int r = j * 32 + w * 4 + (lane >> 4);
      const int sj = (lane & 15) ^ (r & 7);
      gload_lds16(vbase + (size_t)r * 4096 + c * 128 + sj * 8,
                  &Vs[pg][(j * 32 + w * 4) * 128]);
    }
  };

  // Q fragments: B[k][j]: j = lane&31 (q-row), k = g*8+e within each kh*16
  half8 qf[4];
  {
    const _Float16* qp = q + (size_t)(b * TT + qrow0 + l31) * HID + h * DH + g * 8;
    #pragma unroll
    for (int kh = 0; kh < 4; ++kh)
      qf[kh] = *(const half8*)(qp + kh * 16);
  }

  f32x16 acco[2] = {};
  float m_ = -1e30f, l_ = 0.f;       // per-lane state for q = l31

  stageK(0, 0); stageV(0, 0);
  __syncthreads();
  int cur = 0;
  for (int c = 0; c < 4; ++c) {
    if (c + 1 < 4) { stageK(c + 1, cur ^ 1); stageV(c + 1, cur ^ 1); }
    // --- QK^T swapped, 32x32x16: accs[n] = scores s=n*32.., col(l31)=q ---
    f32x16 accs[4] = {};
    __builtin_amdgcn_s_setprio(1);
    #pragma unroll
    for (int n = 0; n < 4; ++n) {
      const int row = n * 32 + l31;
      #pragma unroll
      for (int kh = 0; kh < 4; ++kh) {
        half8 kf = *(const half8*)&Ks[cur][row * 64 + (((kh * 2 + g) ^ key) * 8)];
        accs[n] = __builtin_amdgcn_mfma_f32_32x32x16_f16(kf, qf[kh], accs[n], 0, 0, 0);
      }
    }
    __builtin_amdgcn_s_setprio(0);
    // --- lane-local online softmax (64 in-lane values + cross-half shfl) ---
    float mx = -1e30f;
    #pragma unroll
    for (int n = 0; n < 4; ++n)
      #pragma unroll
      for (int r = 0; r < 16; ++r) mx = fmaxf(mx, accs[n][r]);
    mx = fmaxf(mx, __shfl_xor(mx, 32, 64));
    if (!__all(mx <= m_ + 8.f)) {
      const float mnew = fmaxf(m_, mx);
      const float scale = __expf(m_ - mnew);
      m_ = mnew;
      l_ *= scale;
      #pragma unroll
      for (int df = 0; df < 2; ++df)
        #pragma unroll
        for (int r = 0; r < 16; ++r) acco[df][r] *= scale;
    }
    float sm = 0.f;
    #pragma unroll
    for (int n = 0; n < 4; ++n)
      #pragma unroll
      for (int r = 0; r < 16; ++r) {
        float e = __expf(accs[n][r] - m_);
        accs[n][r] = e;
        sm += e;
      }
    sm += __shfl_xor(sm, 32, 64);
    l_ += sm;
    // --- PV swapped: A=V^T frag (LDS), B=P assembled in regs ---
    #pragma unroll
    for (int n = 0; n < 4; ++n) {
      unsigned int W[8], X[8];
      #pragma unroll
      for (int j = 0; j < 8; ++j)
        W[j] = pkrtz(accs[n][2 * j], accs[n][2 * j + 1]);
      #pragma unroll
      for (int j = 0; j < 8; ++j)
        X[j] = (unsigned int)__shfl_xor((int)W[j], 32, 64);
      union { unsigned int u[4]; half8 h; } be, bo;
      be.u[0] = g ? X[2] : W[0];
      be.u[1] = g ? X[3] : W[1];
      be.u[2] = g ? W[2] : X[0];
      be.u[3] = g ? W[3] : X[1];
      bo.u[0] = g ? X[6] : W[4];
      bo.u[1] = g ? X[7] : W[5];
      bo.u[2] = g ? W[6] : X[4];
      bo.u[3] = g ? W[7] : X[5];
      __builtin_amdgcn_s_setprio(1);
      #pragma unroll
      for (int df = 0; df < 2; ++df) {
        const int rowv = df * 32 + l31;
        const int kv = rowv & 7;
        half8 vfe = *(const half8*)&Vs[cur][rowv * 128 + (((4 * n + g) ^ kv) * 8)];
        acco[df] = __builtin_amdgcn_mfma_f32_32x32x16_f16(vfe, be.h, acco[df], 0, 0, 0);
        half8 vfo = *(const half8*)&Vs[cur][rowv * 128 + (((4 * n + 2 + g) ^ kv) * 8)];
        acco[df] = __builtin_amdgcn_mfma_f32_32x32x16_f16(vfo, bo.h, acco[df], 0, 0, 0);
      }
      __builtin_amdgcn_s_setprio(0);
    }
    if (c < 3) __syncthreads();
    cur ^= 1;
  }
  // all waves done with every PV read before any epilogue staging write
  __syncthreads();
  // --- epilogue: normalize (per-lane inv), stage via retired K/V LDS -------
  const float inv = 1.0f / (l_ * 8.0f);
  _Float16* Os = &Vs[0][0] + w * 2048;   // wave-private 4KB (32q x 64d)
  #pragma unroll
  for (int df = 0; df < 2; ++df) {
    #pragma unroll
    for (int j = 0; j < 8; ++j) {
      const int d = df * 32 + ((j & 1) * 2) + ((j >> 1) * 8) + 4 * g;
      unsigned int pw = pkrtz(acco[df][2 * j] * inv, acco[df][2 * j + 1] * inv);
      *(unsigned int*)((char*)Os + l31 * 128 + (((d >> 3) ^ key) << 4)
                       + (((d >> 1) & 3) << 2)) = pw;
    }
  }
  #pragma unroll
  for (int j2 = 0; j2 < 4; ++j2) {
    const int q2 = j2 * 8 + (lane >> 3);
    const int c2 = lane & 7;
    half8 o = *(const half8*)((const char*)Os + q2 * 128 + (((c2 ^ (q2 & 7)) << 4)));
    _Float16* op = ao + (size_t)(b * TT + qrow0 + q2) * HID + h * DH + c2 * 8;
    *(half8*)op = o;
  }
}

extern "C" void kernel_launch(void* const* d_in, const int* in_sizes, int n_in,
                              void* d_out, int out_size, void* d_ws, size_t ws_size,
                              hipStream_t stream) {
  const float* x     = (const float*)d_in[0];
  const float* media = (const float*)d_in[1];
  // d_in[2] media_locations: unused (reference discards the mask)
  const float* Wq    = (const float*)d_in[3];
  const float* Wkv   = (const float*)d_in[4];
  const float* Wo    = (const float*)d_in[5];
  const float* gamma = (const float*)d_in[6];
  const float* beta  = (const float*)d_in[7];
  float* out = (float*)d_out;

  char* ws = (char*)d_ws;
  _Float16* xn     = (_Float16*)(ws);                    // 8192x2048 (32MB)
  _Float16* qh     = (_Float16*)(ws + 33554432);         // 8192x1024 (16MB)
  _Float16* kh     = (_Float16*)(ws + 50331648);         // 4096x1024 (8MB)
  _Float16* vth    = (_Float16*)(ws + 58720256);         // 1024x4096 (8MB)
  _Float16* aoh    = (_Float16*)(ws + 67108864);         // 8192x1024 (16MB)
  _Float16* mediah = (_Float16*)(ws + 83886080);         // 4096x1024 (8MB)
  _Float16* wqT    = (_Float16*)(ws + 92274688);         // 1024x2048 (4MB)
  _Float16* wkvT   = (_Float16*)(ws + 96468992);         // 2048x1024 (4MB)
  _Float16* woT    = (_Float16*)(ws + 100663296);        // 2048x1024 (4MB)

  prep<<<dim3(18432), dim3(256), 0, stream>>>(
      x, gamma, beta, xn, Wq, wqT, Wkv, wkvT, Wo, woT, media, mediah);
  gemm_qkv<<<dim3(1024), dim3(256), 0, stream>>>(xn, wqT, qh, mediah, wkvT, kh, vth);
  attn_kernel<<<dim3(512), dim3(512), 0, stream>>>(qh, kh, vth, aoh);
  gemm_out<<<dim3(256), dim3(512), 0, stream>>>(aoh, woT, out);
}

// Round 17
// 165.172 us; speedup vs baseline: 1.0766x; 1.0258x over previous
//
#include <hip/hip_runtime.h>
#include <hip/hip_bf16.h>
#include <stdint.h>

#define B_     8
#define TT     1024
#define DIM_   2048
#define S_     512
#define H_     16
#define DH     64
#define HID    1024

typedef _Float16 half8 __attribute__((ext_vector_type(8)));
typedef _Float16 half4v __attribute__((ext_vector_type(4)));
typedef float f32x4 __attribute__((ext_vector_type(4)));
typedef float f32x16 __attribute__((ext_vector_type(16)));

__device__ __forceinline__ void gload_lds16(const void* g, void* l) {
  __builtin_amdgcn_global_load_lds(
      (__attribute__((address_space(1))) unsigned int*)(uintptr_t)g,
      (__attribute__((address_space(3))) unsigned int*)l, 16, 0, 0);
}

__device__ __forceinline__ unsigned int pkrtz(float a, float b) {
  auto h = __builtin_amdgcn_cvt_pkrtz(a, b);   // __fp16 ext_vector(2)
  return __builtin_bit_cast(unsigned int, h);
}

#define MFMA16(afv, bfv, nh)                                                  \
  do {                                                                        \
    __builtin_amdgcn_s_setprio(1);                                            \
    _Pragma("unroll")                                                         \
    for (int m_ = 0; m_ < 8; ++m_) {                                          \
      acc[m_][(nh)*2]   = __builtin_amdgcn_mfma_f32_16x16x32_f16(             \
          afv[m_], bfv[0], acc[m_][(nh)*2], 0, 0, 0);                         \
      acc[m_][(nh)*2+1] = __builtin_amdgcn_mfma_f32_16x16x32_f16(             \
          afv[m_], bfv[1], acc[m_][(nh)*2+1], 0, 0, 0);                       \
    }                                                                         \
    __builtin_amdgcn_s_setprio(0);                                            \
  } while (0)

// ---------------- fused prep: LN+cast, 3 weight transposes, media cast -----
__device__ __forceinline__ void transpose_tile(
    const float* __restrict__ in, _Float16* __restrict__ out,
    int R, int C, int bx, int by, float (*t)[33])
{
  const int tid = threadIdx.x;
  const int tx = tid & 31, ty = tid >> 5;
  const int c0 = bx * 32, r0 = by * 32;
  #pragma unroll
  for (int i = 0; i < 32; i += 8)
    t[ty + i][tx] = in[(size_t)(r0 + ty + i) * C + c0 + tx];
  __syncthreads();
  #pragma unroll
  for (int i = 0; i < 32; i += 8)
    out[(size_t)(c0 + ty + i) * R + r0 + tx] = (_Float16)t[tx][ty + i];
}

__global__ __launch_bounds__(256) void prep(
    const float* __restrict__ x, const float* __restrict__ gamma,
    const float* __restrict__ beta, _Float16* __restrict__ xn,
    const float* __restrict__ Wq,  _Float16* __restrict__ wqT,
    const float* __restrict__ Wkv, _Float16* __restrict__ wkvT,
    const float* __restrict__ Wo,  _Float16* __restrict__ woT,
    const float* __restrict__ media, _Float16* __restrict__ mediah)
{
  __shared__ float t[32][33];
  const int id = blockIdx.x;
  const int tid = threadIdx.x;
  if (id < 8192) {
    const float* xr = x + (size_t)id * DIM_;
    float4 a = ((const float4*)xr)[tid * 2];
    float4 b = ((const float4*)xr)[tid * 2 + 1];
    float s1 = a.x + a.y + a.z + a.w + b.x + b.y + b.z + b.w;
    float s2 = a.x*a.x + a.y*a.y + a.z*a.z + a.w*a.w
             + b.x*b.x + b.y*b.y + b.z*b.z + b.w*b.w;
    #pragma unroll
    for (int d = 1; d < 64; d <<= 1) {
      s1 += __shfl_xor(s1, d, 64);
      s2 += __shfl_xor(s2, d, 64);
    }
    const int w = tid >> 6, lane = tid & 63;
    if (lane == 0) { t[0][w] = s1; t[0][4 + w] = s2; }
    __syncthreads();
    s1 = t[0][0] + t[0][1] + t[0][2] + t[0][3];
    s2 = t[0][4] + t[0][5] + t[0][6] + t[0][7];
    const float mu  = s1 * (1.0f / DIM_);
    const float var = s2 * (1.0f / DIM_) - mu * mu;
    const float rs  = rsqrtf(var + 1e-5f);
    float4 g0 = ((const float4*)gamma)[tid * 2];
    float4 g1 = ((const float4*)gamma)[tid * 2 + 1];
    float4 e0 = ((const float4*)beta)[tid * 2];
    float4 e1 = ((const float4*)beta)[tid * 2 + 1];
    half8 o;
    o[0] = (_Float16)((a.x - mu) * rs * g0.x + e0.x);
    o[1] = (_Float16)((a.y - mu) * rs * g0.y + e0.y);
    o[2] = (_Float16)((a.z - mu) * rs * g0.z + e0.z);
    o[3] = (_Float16)((a.w - mu) * rs * g0.w + e0.w);
    o[4] = (_Float16)((b.x - mu) * rs * g1.x + e1.x);
    o[5] = (_Float16)((b.y - mu) * rs * g1.y + e1.y);
    o[6] = (_Float16)((b.z - mu) * rs * g1.z + e1.z);
    o[7] = (_Float16)((b.w - mu) * rs * g1.w + e1.w);
    *(half8*)(xn + (size_t)id * DIM_ + tid * 8) = o;
  } else if (id < 10240) {
    const int lid = id - 8192;
    transpose_tile(Wq, wqT, 2048, 1024, lid & 31, lid >> 5, t);
  } else if (id < 12288) {
    const int lid = id - 10240;
    transpose_tile(Wkv, wkvT, 1024, 2048, lid & 63, lid >> 6, t);
  } else if (id < 14336) {
    const int lid = id - 12288;
    transpose_tile(Wo, woT, 1024, 2048, lid & 63, lid >> 6, t);
  } else {
    const int i = (id - 14336) * 256 + tid;
    float4 v = ((const float4*)media)[i];
    half4v o;
    o[0] = (_Float16)v.x; o[1] = (_Float16)v.y;
    o[2] = (_Float16)v.z; o[3] = (_Float16)v.w;
    ((half4v*)mediah)[i] = o;
  }
}

// ---------------- 128x128 GEMM, BK=32, 4 waves, m97-style loop -------------
template<typename OutT>
__device__ __forceinline__ void gemm128_body(
    const _Float16* __restrict__ A, const _Float16* __restrict__ BT,
    OutT* __restrict__ C, int KD, int ND, int m0, int n0,
    _Float16* __restrict__ sA, _Float16* __restrict__ sB)
{
  const int tid = threadIdx.x;
  const int lane = tid & 63, w = tid >> 6;
  const int l15 = lane & 15, lhi = lane >> 4;
  const int wr = w >> 1, wc = w & 1;
  const int rr = tid >> 2;
  const int sc = (tid & 3) ^ ((rr >> 1) & 3);

  auto stage = [&](const _Float16* __restrict__ G, int base, int k0,
                   _Float16* dst) {
    #pragma unroll
    for (int j = 0; j < 2; ++j) {
      const int r = j * 64 + rr;
      gload_lds16(G + (size_t)(base + r) * KD + k0 + sc * 8,
                  dst + j * 2048 + w * 512);
    }
  };

  f32x4 acc[4][4] = {};
  const int NT = KD >> 5;
  const int ck = lhi ^ ((l15 >> 1) & 3);

  stage(A, m0, 0, sA);
  stage(BT, n0, 0, sB);
  __syncthreads();
  int cur = 0;
  for (int kt = 0; kt < NT; ++kt) {
    if (kt + 1 < NT) {
      stage(A, m0, (kt + 1) * 32, sA + (cur ^ 1) * 4096);
      stage(BT, n0, (kt + 1) * 32, sB + (cur ^ 1) * 4096);
    }
    const _Float16* cA = sA + cur * 4096;
    const _Float16* cB = sB + cur * 4096;
    half8 af[4], bf[4];
    #pragma unroll
    for (int m = 0; m < 4; ++m)
      af[m] = *(const half8*)&cA[(wr * 64 + m * 16 + l15) * 32 + ck * 8];
    #pragma unroll
    for (int n = 0; n < 4; ++n)
      bf[n] = *(const half8*)&cB[(wc * 64 + n * 16 + l15) * 32 + ck * 8];
    #pragma unroll
    for (int m = 0; m < 4; ++m)
      #pragma unroll
      for (int n = 0; n < 4; ++n)
        acc[m][n] = __builtin_amdgcn_mfma_f32_16x16x32_f16(
            af[m], bf[n], acc[m][n], 0, 0, 0);
    __syncthreads();
    cur ^= 1;
  }

  #pragma unroll
  for (int m = 0; m < 4; ++m) {
    const int row = m0 + wr * 64 + m * 16 + lhi * 4;
    #pragma unroll
    for (int n = 0; n < 4; ++n) {
      const int col = n0 + wc * 64 + n * 16 + l15;
      #pragma unroll
      for (int r = 0; r < 4; ++r)
        C[(size_t)(row + r) * ND + col] = (OutT)acc[m][n][r];
    }
  }
}

// Fused Q + K + V^T: 512+256+256 = 1024 blocks = 4/CU.
__global__ __launch_bounds__(256, 4) void gemm_qkv(
    const _Float16* __restrict__ xn, const _Float16* __restrict__ wqT,
    _Float16* __restrict__ qh,
    const _Float16* __restrict__ mediah, const _Float16* __restrict__ wkvT,
    _Float16* __restrict__ kmat, _Float16* __restrict__ vth)
{
  __shared__ __align__(16) _Float16 sA[2 * 4096], sB[2 * 4096];
  const int id = blockIdx.x;
  if (id < 512) {              // Q: M=8192 N=1024 K=2048
    const int m = id & 63, n = id >> 6;
    gemm128_body<_Float16>(xn, wqT, qh, 2048, 1024, m * 128, n * 128, sA, sB);
  } else if (id < 768) {       // K: M=4096 N=1024 K=1024
    const int lid = id - 512;
    const int m = lid & 31, n = lid >> 5;
    gemm128_body<_Float16>(mediah, wkvT, kmat, 1024, 1024, m * 128, n * 128, sA, sB);
  } else {                     // V^T: M=1024 N=4096 K=1024
    const int lid = id - 768;
    const int m = lid & 7, n = lid >> 3;
    gemm128_body<_Float16>(wkvT + 1024 * 1024, mediah, vth, 1024, 4096,
                           m * 128, n * 128, sA, sB);
  }
}

// ---------------- 256x256 GEMM, BK=64, 8-phase counted-vmcnt (out-proj) ----
template<int KD, int ND, typename OutT>
__device__ __forceinline__ void gemm256_body(
    const _Float16* __restrict__ A, const _Float16* __restrict__ BT,
    OutT* __restrict__ C, int m0, int n0,
    _Float16* __restrict__ sAe, _Float16* __restrict__ sAo,
    _Float16* __restrict__ sBe, _Float16* __restrict__ sBo)
{
  constexpr int NT = KD / 64;
  constexpr int NI = NT / 2;
  const int tid = threadIdx.x;
  const int lane = tid & 63, w = tid >> 6;
  const int l15 = lane & 15, lhi = lane >> 4;
  const int wr = w >> 2, wc = w & 3;
  const int rs = l15 & 7;
  const int srow = tid >> 3;
  const int sch = (tid & 7) ^ (srow & 7);

  auto stage = [&](const _Float16* __restrict__ G, int base, int kt, int h,
                   _Float16* __restrict__ dst) {
    #pragma unroll
    for (int j = 0; j < 2; ++j) {
      const int r = h * 128 + j * 64 + srow;
      gload_lds16(G + (size_t)(base + r) * KD + kt * 64 + sch * 8,
                  dst + h * 8192 + j * 4096 + w * 512);
    }
  };

  f32x4 acc[8][4] = {};
  half8 af0[8], af1[8], bf0[2], bf1[2];

  stage(A,  m0, 0, 0, sAe); stage(A,  m0, 0, 1, sAe);
  stage(BT, n0, 0, 0, sBe); stage(BT, n0, 0, 1, sBe);
  stage(A,  m0, 1, 0, sAo); stage(A,  m0, 1, 1, sAo);
  asm volatile("s_waitcnt vmcnt(4)" ::: "memory");
  __builtin_amdgcn_s_barrier();

  for (int it = 0; it < NI; ++it) {
    const bool pf = (it + 1 < NI);
    const int t1 = 2 * it + 1, tn0 = 2 * it + 2, tn1 = 2 * it + 3;

    #pragma unroll
    for (int m = 0; m < 8; ++m)
      af0[m] = *(const half8*)&sAe[(wr*128 + m*16 + l15)*64 + ((lhi ^ rs)*8)];
    #pragma unroll
    for (int n = 0; n < 2; ++n)
      bf0[n] = *(const half8*)&sBe[(wc*64 + n*16 + l15)*64 + ((lhi ^ rs)*8)];
    stage(BT, n0, t1, 0, sBo);
    __builtin_amdgcn_s_barrier();
    asm volatile("s_waitcnt lgkmcnt(0)" ::: "memory");
    MFMA16(af0, bf0, 0);
    __builtin_amdgcn_s_barrier();
    #pragma unroll
    for (int m = 0; m < 8; ++m)
      af1[m] = *(const half8*)&sAe[(wr*128 + m*16 + l15)*64 + (((4+lhi) ^ rs)*8)];
    #pragma unroll
    for (int n = 0; n < 2; ++n)
      bf1[n] = *(const half8*)&sBe[(wc*64 + (2+n)*16 + l15)*64 + ((lhi ^ rs)*8)];
    stage(BT, n0, t1, 1, sBo);
    __builtin_amdgcn_s_barrier();
    asm volatile("s_waitcnt lgkmcnt(0)" ::: "memory");
    MFMA16(af0, bf1, 1);
    __builtin_amdgcn_s_barrier();
    #pragma unroll
    for (int n = 0; n < 2; ++n)
      bf0[n] = *(const half8*)&sBe[(wc*64 + n*16 + l15)*64 + (((4+lhi) ^ rs)*8)];
    if (pf) stage(A, m0, tn0, 0, sAe);
    __builtin_amdgcn_s_barrier();
    asm volatile("s_waitcnt lgkmcnt(0)" ::: "memory");
    MFMA16(af1, bf0, 0);
    __builtin_amdgcn_s_barrier();
    #pragma unroll
    for (int n = 0; n < 2; ++n)
      bf1[n] = *(const half8*)&sBe[(wc*64 + (2+n)*16 + l15)*64 + (((4+lhi) ^ rs)*8)];
    if (pf) stage(A, m0, tn0, 1, sAe);
    __builtin_amdgcn_s_barrier();
    asm volatile("s_waitcnt lgkmcnt(0)" ::: "memory");
    MFMA16(af1, bf1, 1);
    if (pf) asm volatile("s_waitcnt vmcnt(4)" ::: "memory");
    else    asm volatile("s_waitcnt vmcnt(0)" ::: "memory");
    __builtin_amdgcn_s_barrier();

    #pragma unroll
    for (int m = 0; m < 8; ++m)
      af0[m] = *(const half8*)&sAo[(wr*128 + m*16 + l15)*64 + ((lhi ^ rs)*8)];
    #pragma unroll
    for (int n = 0; n < 2; ++n)
      bf0[n] = *(const half8*)&sBo[(wc*64 + n*16 + l15)*64 + ((lhi ^ rs)*8)];
    if (pf) stage(BT, n0, tn0, 0, sBe);
    __builtin_amdgcn_s_barrier();
    asm volatile("s_waitcnt lgkmcnt(0)" ::: "memory");
    MFMA16(af0, bf0, 0);
    __builtin_amdgcn_s_barrier();
    #pragma unroll
    for (int m = 0; m < 8; ++m)
      af1[m] = *(const half8*)&sAo[(wr*128 + m*16 + l15)*64 + (((4+lhi) ^ rs)*8)];
    #pragma unroll
    for (int n = 0; n < 2; ++n)
      bf1[n] = *(const half8*)&sBo[(wc*64 + (2+n)*16 + l15)*64 + ((lhi ^ rs)*8)];
    if (pf) stage(BT, n0, tn0, 1, sBe);
    __builtin_amdgcn_s_barrier();
    asm volatile("s_waitcnt lgkmcnt(0)" ::: "memory");
    MFMA16(af0, bf1, 1);
    __builtin_amdgcn_s_barrier();
    #pragma unroll
    for (int n = 0; n < 2; ++n)
      bf0[n] = *(const half8*)&sBo[(wc*64 + n*16 + l15)*64 + (((4+lhi) ^ rs)*8)];
    if (pf) stage(A, m0, tn1, 0, sAo);
    __builtin_amdgcn_s_barrier();
    asm volatile("s_waitcnt lgkmcnt(0)" ::: "memory");
    MFMA16(af1, bf0, 0);
    __builtin_amdgcn_s_barrier();
    #pragma unroll
    for (int n = 0; n < 2; ++n)
      bf1[n] = *(const half8*)&sBo[(wc*64 + (2+n)*16 + l15)*64 + (((4+lhi) ^ rs)*8)];
    if (pf) stage(A, m0, tn1, 1, sAo);
    __builtin_amdgcn_s_barrier();
    asm volatile("s_waitcnt lgkmcnt(0)" ::: "memory");
    MFMA16(af1, bf1, 1);
    if (pf) asm volatile("s_waitcnt vmcnt(4)" ::: "memory");
    else    asm volatile("s_waitcnt vmcnt(0)" ::: "memory");
    __builtin_amdgcn_s_barrier();
  }

  #pragma unroll
  for (int mf = 0; mf < 8; ++mf) {
    const int row = m0 + wr * 128 + mf * 16 + lhi * 4;
    #pragma unroll
    for (int nf = 0; nf < 4; ++nf) {
      const int col = n0 + wc * 64 + nf * 16 + l15;
      #pragma unroll
      for (int r = 0; r < 4; ++r)
        C[(size_t)(row + r) * ND + col] = (OutT)acc[mf][nf][r];
    }
  }
}

__global__ __launch_bounds__(512, 2) void gemm_out(
    const _Float16* __restrict__ aoh, const _Float16* __restrict__ woT,
    float* __restrict__ out)
{
  __shared__ __align__(16) _Float16 sAe[256 * 64], sAo[256 * 64];
  __shared__ __align__(16) _Float16 sBe[256 * 64], sBo[256 * 64];
  const int id = blockIdx.x;
  const int m = id & 31, n = id >> 5;
  gemm256_body<1024, 2048, float>(aoh, woT, out, m * 256, n * 256,
                                  sAe, sAo, sBe, sBo);
}

// ---------------- fused attention v10: 32x32x16, KVBLK=64, low-VGPR --------
// v9b with KVBLK 128->64: accs[2] f32x16 (32 VGPR vs 64) targets <=128 VGPR
// -> 4 waves/SIMD (16 waves/CU) instead of VGPR-capped 3. LDS 32KB (2x8KB K
// + 2x8KB V dbuf). All fragment mappings identical (chunk-local); 8 chunks,
// online softmax + defer-max, in-register P via pkrtz + shfl_xor(32).
__global__ __launch_bounds__(512, 4) void attn_kernel(
    const _Float16* __restrict__ q, const _Float16* __restrict__ kmat,
    const _Float16* __restrict__ vt, _Float16* __restrict__ ao)
{
  __shared__ __align__(16) _Float16 Ks[2][64 * 64];   // 8 KB each
  __shared__ __align__(16) _Float16 Vs[2][64 * 64];   // 8 KB each
  const int tid = threadIdx.x;
  const int lane = tid & 63, w = tid >> 6;
  const int l31 = lane & 31, g = lane >> 5;
  const int key = l31 & 7;
  const int id = blockIdx.x;
  const int bh = id & 127, qq = id >> 7;
  const int b = bh >> 4, h = bh & 15;
  const int qrow0 = qq * 256 + w * 32;

  const _Float16* kbase = kmat + (size_t)(b * S_) * 1024 + h * DH;
  const _Float16* vbase = vt + (size_t)(h * DH) * 4096 + b * S_;

  // K chunk: 64 s-rows x 64 d; 1 gload/thread. row r = w*8+(l>>3).
  auto stageK = [&](int c, int pg) {
    const int r = w * 8 + (lane >> 3);
    const int sj = (lane & 7) ^ (r & 7);
    gload_lds16(kbase + (size_t)(c * 64 + r) * 1024 + sj * 8, &Ks[pg][w * 512]);
  };
  // V^T chunk: 64 d-rows x 64 s; 1 gload/thread.
  auto stageV = [&](int c, int pg) {
    const int r = w * 8 + (lane >> 3);
    const int sj = (lane & 7) ^ (r & 7);
    gload_lds16(vbase + (size_t)r * 4096 + c * 64 + sj * 8, &Vs[pg][w * 512]);
  };

  // Q fragments: B[k][j]: j = lane&31 (q-row), k = g*8+e within each kh*16
  half8 qf[4];
  {
    const _Float16* qp = q + (size_t)(b * TT + qrow0 + l31) * HID + h * DH + g * 8;
    #pragma unroll
    for (int kh = 0; kh < 4; ++kh)
      qf[kh] = *(const half8*)(qp + kh * 16);
  }

  f32x16 acco[2] = {};
  float m_ = -1e30f, l_ = 0.f;       // per-lane state for q = l31

  stageK(0, 0); stageV(0, 0);
  __syncthreads();
  int cur = 0;
  for (int c = 0; c < 8; ++c) {
    if (c + 1 < 8) { stageK(c + 1, cur ^ 1); stageV(c + 1, cur ^ 1); }
    // --- QK^T swapped, 32x32x16: accs[n] = scores s=n*32.., col(l31)=q ---
    f32x16 accs[2] = {};
    __builtin_amdgcn_s_setprio(1);
    #pragma unroll
    for (int n = 0; n < 2; ++n) {
      const int row = n * 32 + l31;
      #pragma unroll
      for (int kh = 0; kh < 4; ++kh) {
        half8 kf = *(const half8*)&Ks[cur][row * 64 + (((kh * 2 + g) ^ key) * 8)];
        accs[n] = __builtin_amdgcn_mfma_f32_32x32x16_f16(kf, qf[kh], accs[n], 0, 0, 0);
      }
    }
    __builtin_amdgcn_s_setprio(0);
    // --- lane-local online softmax (32 in-lane values + cross-half shfl) ---
    float mx = -1e30f;
    #pragma unroll
    for (int n = 0; n < 2; ++n)
      #pragma unroll
      for (int r = 0; r < 16; ++r) mx = fmaxf(mx, accs[n][r]);
    mx = fmaxf(mx, __shfl_xor(mx, 32, 64));
    if (!__all(mx <= m_ + 8.f)) {
      const float mnew = fmaxf(m_, mx);
      const float scale = __expf(m_ - mnew);
      m_ = mnew;
      l_ *= scale;
      #pragma unroll
      for (int df = 0; df < 2; ++df)
        #pragma unroll
        for (int r = 0; r < 16; ++r) acco[df][r] *= scale;
    }
    float sm = 0.f;
    #pragma unroll
    for (int n = 0; n < 2; ++n)
      #pragma unroll
      for (int r = 0; r < 16; ++r) {
        float e = __expf(accs[n][r] - m_);
        accs[n][r] = e;
        sm += e;
      }
    sm += __shfl_xor(sm, 32, 64);
    l_ += sm;
    // --- PV swapped: A=V^T frag (LDS), B=P assembled in regs ---
    #pragma unroll
    for (int n = 0; n < 2; ++n) {
      unsigned int W[8], X[8];
      #pragma unroll
      for (int j = 0; j < 8; ++j)
        W[j] = pkrtz(accs[n][2 * j], accs[n][2 * j + 1]);
      #pragma unroll
      for (int j = 0; j < 8; ++j)
        X[j] = (unsigned int)__shfl_xor((int)W[j], 32, 64);
      union { unsigned int u[4]; half8 h; } be, bo;
      be.u[0] = g ? X[2] : W[0];
      be.u[1] = g ? X[3] : W[1];
      be.u[2] = g ? W[2] : X[0];
      be.u[3] = g ? W[3] : X[1];
      bo.u[0] = g ? X[6] : W[4];
      bo.u[1] = g ? X[7] : W[5];
      bo.u[2] = g ? W[6] : X[4];
      bo.u[3] = g ? W[7] : X[5];
      __builtin_amdgcn_s_setprio(1);
      #pragma unroll
      for (int df = 0; df < 2; ++df) {
        const int rowv = df * 32 + l31;
        const int kv = rowv & 7;
        half8 vfe = *(const half8*)&Vs[cur][rowv * 64 + (((4 * n + g) ^ kv) * 8)];
        acco[df] = __builtin_amdgcn_mfma_f32_32x32x16_f16(vfe, be.h, acco[df], 0, 0, 0);
        half8 vfo = *(const half8*)&Vs[cur][rowv * 64 + (((4 * n + 2 + g) ^ kv) * 8)];
        acco[df] = __builtin_amdgcn_mfma_f32_32x32x16_f16(vfo, bo.h, acco[df], 0, 0, 0);
      }
      __builtin_amdgcn_s_setprio(0);
    }
    if (c < 7) __syncthreads();
    cur ^= 1;
  }
  // all waves done with every PV read before any epilogue staging write
  __syncthreads();
  // --- epilogue: normalize (per-lane inv), stage via retired K/V LDS -------
  const float inv = 1.0f / (l_ * 8.0f);
  _Float16* Os = &Ks[0][0] + w * 2048;   // wave-private 4KB (32q x 64d)
  #pragma unroll
  for (int df = 0; df < 2; ++df) {
    #pragma unroll
    for (int j = 0; j < 8; ++j) {
      const int d = df * 32 + ((j & 1) * 2) + ((j >> 1) * 8) + 4 * g;
      unsigned int pw = pkrtz(acco[df][2 * j] * inv, acco[df][2 * j + 1] * inv);
      *(unsigned int*)((char*)Os + l31 * 128 + (((d >> 3) ^ key) << 4)
                       + (((d >> 1) & 3) << 2)) = pw;
    }
  }
  #pragma unroll
  for (int j2 = 0; j2 < 4; ++j2) {
    const int q2 = j2 * 8 + (lane >> 3);
    const int c2 = lane & 7;
    half8 o = *(const half8*)((const char*)Os + q2 * 128 + (((c2 ^ (q2 & 7)) << 4)));
    _Float16* op = ao + (size_t)(b * TT + qrow0 + q2) * HID + h * DH + c2 * 8;
    *(half8*)op = o;
  }
}

extern "C" void kernel_launch(void* const* d_in, const int* in_sizes, int n_in,
                              void* d_out, int out_size, void* d_ws, size_t ws_size,
                              hipStream_t stream) {
  const float* x     = (const float*)d_in[0];
  const float* media = (const float*)d_in[1];
  // d_in[2] media_locations: unused (reference discards the mask)
  const float* Wq    = (const float*)d_in[3];
  const float* Wkv   = (const float*)d_in[4];
  const float* Wo    = (const float*)d_in[5];
  const float* gamma = (const float*)d_in[6];
  const float* beta  = (const float*)d_in[7];
  float* out = (float*)d_out;

  char* ws = (char*)d_ws;
  _Float16* xn     = (_Float16*)(ws);                    // 8192x2048 (32MB)
  _Float16* qh     = (_Float16*)(ws + 33554432);         // 8192x1024 (16MB)
  _Float16* kh     = (_Float16*)(ws + 50331648);         // 4096x1024 (8MB)
  _Float16* vth    = (_Float16*)(ws + 58720256);         // 1024x4096 (8MB)
  _Float16* aoh    = (_Float16*)(ws + 67108864);         // 8192x1024 (16MB)
  _Float16* mediah = (_Float16*)(ws + 83886080);         // 4096x1024 (8MB)
  _Float16* wqT    = (_Float16*)(ws + 92274688);         // 1024x2048 (4MB)
  _Float16* wkvT   = (_Float16*)(ws + 96468992);         // 2048x1024 (4MB)
  _Float16* woT    = (_Float16*)(ws + 100663296);        // 2048x1024 (4MB)

  prep<<<dim3(18432), dim3(256), 0, stream>>>(
      x, gamma, beta, xn, Wq, wqT, Wkv, wkvT, Wo, woT, media, mediah);
  gemm_qkv<<<dim3(1024), dim3(256), 0, stream>>>(xn, wqT, qh, mediah, wkvT, kh, vth);
  attn_kernel<<<dim3(512), dim3(512), 0, stream>>>(qh, kh, vth, aoh);
  gemm_out<<<dim3(256), dim3(512), 0, stream>>>(aoh, woT, out);
}